// Round 1
// baseline (152.251 us; speedup 1.0000x reference)
//
#include <hip/hip_runtime.h>
#include <math.h>

typedef __attribute__((ext_vector_type(8))) short short8;
typedef __attribute__((ext_vector_type(4))) float f32x4;

#if __has_builtin(__builtin_amdgcn_exp2f)
#define EXP2F(x) __builtin_amdgcn_exp2f(x)
#else
#define EXP2F(x) exp2f(x)
#endif

constexpr int B   = 4;
constexpr int N   = 2304;
constexpr int DIM = 256;
constexpr int NH  = 8;
constexpr int DH  = 32;
constexpr int M   = B * N;          // 9216 rows
constexpr int SLOTS = 2336;         // N + 32: kept keys + pad + masked keys
constexpr int CST = SLOTS * DH;     // per-(b,h) compact K/V element count
constexpr int XPB = SLOTS * DIM;    // per-batch permuted-xn element count
constexpr float LOG2E = 1.44269504088896f;

// float -> bf16 round-to-nearest-even, and back
__device__ inline unsigned short f2bf(float f) {
    union { float f; unsigned u; } c; c.f = f;
    unsigned u = c.u;
    u += 0x7fffu + ((u >> 16) & 1u);
    return (unsigned short)(u >> 16);
}
__device__ inline float bf2f(unsigned short h) {
    union { unsigned u; float f; } c; c.u = ((unsigned)h) << 16;
    return c.f;
}
__device__ inline unsigned bits(float f) {
    union { float f; unsigned u; } c; c.f = f; return c.u;
}

// ---- FragTile layouts: element (row r, contraction k) stored so an MFMA
// A/B-frag load (16 rows x 32 k) is ONE contiguous 1KB wave transaction.
__device__ inline size_t fo256(int r, int k) {   // [R x 256] tensors
    return ((size_t)((r >> 4) * 8 + (k >> 5)) << 9)
         + (size_t)(((((k & 31) >> 3) << 4) + (r & 15)) * 8 + (k & 7));
}
__device__ inline size_t foQK(int n, int d) {    // per-(b,h) [rows x 32]
    return ((size_t)(n >> 4) << 9)
         + (size_t)((((d >> 3) << 4) + (n & 15)) * 8 + (d & 7));
}
// K with even/odd interleave: within each 32-slot chunk, even slots fill the
// first 16-tile, odd slots the second -> packed b32 LDS writes in attn.
__device__ inline size_t foKI(int slot, int d) {
    int tile = ((slot >> 5) << 1) + (slot & 1);
    int npos = (slot & 31) >> 1;
    return ((size_t)tile << 9)
         + (size_t)((((d >> 3) << 4) + npos) * 8 + (d & 7));
}
__device__ inline size_t foVTC(int d, int key) { // per-(b,h) [32 x SLOTS]
    return ((size_t)((d >> 4) * (SLOTS / 32) + (key >> 5)) << 9)
         + (size_t)(((((key & 31) >> 3) << 4) + (d & 15)) * 8 + (key & 7));
}

// ------------- fused prep: LN (hi only) | split_w | mask_scan --------------
__global__ __launch_bounds__(256) void prep_kernel(
    const float* __restrict__ x, const float* __restrict__ g,
    const float* __restrict__ bta, unsigned short* __restrict__ xh,
    const float* __restrict__ Wq, const float* __restrict__ Wk,
    const float* __restrict__ Wv, const float* __restrict__ Wp,
    unsigned short* __restrict__ Wth, unsigned short* __restrict__ Wtl,
    const float* __restrict__ mask, int* __restrict__ inv,
    int* __restrict__ ncp, float* __restrict__ vm)
{
    __shared__ float tbuf[32][33];
    __shared__ int wsum[4];
    int bx = blockIdx.x;
    int t = threadIdx.x;
    if (bx < 2304) {
        // ---- LayerNorm, one wave per row ----
        int wave = t >> 6, lane = t & 63;
        int row = bx * 4 + wave;
        float4 v = *(const float4*)&x[(size_t)row * DIM + lane * 4];
        float s = v.x + v.y + v.z + v.w;
        #pragma unroll
        for (int o = 32; o > 0; o >>= 1) s += __shfl_xor(s, o, 64);
        float mu = s * (1.0f / DIM);
        float d0 = v.x - mu, d1 = v.y - mu, d2 = v.z - mu, d3 = v.w - mu;
        float s2 = d0 * d0 + d1 * d1 + d2 * d2 + d3 * d3;
        #pragma unroll
        for (int o = 32; o > 0; o >>= 1) s2 += __shfl_xor(s2, o, 64);
        float r = rsqrtf(s2 * (1.0f / DIM) + 1e-5f);
        float4 gg = *(const float4*)&g[lane * 4];
        float4 bb = *(const float4*)&bta[lane * 4];
        ushort4 hi;
        hi.x = f2bf(d0 * r * gg.x + bb.x);
        hi.y = f2bf(d1 * r * gg.y + bb.y);
        hi.z = f2bf(d2 * r * gg.z + bb.z);
        hi.w = f2bf(d3 * r * gg.w + bb.w);
        *(ushort4*)&xh[fo256(row, lane * 4)] = hi;
    } else if (bx < 2560) {
        // ---- weight transpose + hi/lo split (lo used only by gemm_p) ----
        int idx = bx - 2304;
        int z = idx >> 6, w = idx & 63;
        const float* W = (z == 0) ? Wq : (z == 1) ? Wk : (z == 2) ? Wv : Wp;
        unsigned short* oh = Wth + (size_t)z * DIM * DIM;
        unsigned short* ol = Wtl + (size_t)z * DIM * DIM;
        int tx = t & 31, ty0 = t >> 5;
        int n0 = (w & 7) * 32, k0 = (w >> 3) * 32;
        for (int ty = ty0; ty < 32; ty += 8)
            tbuf[ty][tx] = W[(size_t)(k0 + ty) * DIM + n0 + tx];
        __syncthreads();
        for (int nn = ty0; nn < 32; nn += 8) {
            float v = tbuf[tx][nn];          // = Wt[n0+nn][k0+tx]
            unsigned short hh = f2bf(v);
            size_t o = fo256(n0 + nn, k0 + tx);
            oh[o] = hh;
            ol[o] = f2bf(v - bf2f(hh));
        }
    } else {
        // ---- mask scan (one block per batch) + zero vm ----
        int b = bx - 2560;
        int wave = t >> 6, lane = t & 63;
        vm[b * 256 + t] = 0.f;               // vm is B*NH*32 = 1024 floats
        int cnt = 0;
        for (int j = t; j < N; j += 256) cnt += (mask[(size_t)b * N + j] > 0.f);
        #pragma unroll
        for (int o = 32; o > 0; o >>= 1) cnt += __shfl_down(cnt, o, 64);
        if (lane == 0) wsum[wave] = cnt;
        __syncthreads();
        int Nc = wsum[0] + wsum[1] + wsum[2] + wsum[3];
        int Nkp = (Nc + 31) & ~31;
        if (t == 0) { ncp[b * 2] = Nc; ncp[b * 2 + 1] = Nkp; }
        int baseK = 0;
        for (int j0 = 0; j0 < N; j0 += 256) {
            int j = j0 + t;
            bool keep = mask[(size_t)b * N + j] > 0.f;
            unsigned long long bal = __ballot(keep);
            int pos = __popcll(bal & ((1ull << lane) - 1ull));
            int wc  = __popcll(bal);
            __syncthreads();
            if (lane == 0) wsum[wave] = wc;
            __syncthreads();
            int wb = 0;
            for (int w = 0; w < wave; ++w) wb += wsum[w];
            int tot = wsum[0] + wsum[1] + wsum[2] + wsum[3];
            int keptBefore = baseK + wb + pos;
            if (keep) inv[(size_t)b * SLOTS + keptBefore] = j;
            else      inv[(size_t)b * SLOTS + Nkp + (j - keptBefore)] = j;
            baseK += tot;
        }
    }
}

// ------- permute xn rows (hi only) by slot order, per batch ----------------
__global__ __launch_bounds__(256) void permute_x(
    const unsigned short* __restrict__ xh,
    const int* __restrict__ inv, const int* __restrict__ ncp,
    unsigned short* __restrict__ xph)
{
    int tid = threadIdx.x;
    int wave = tid >> 6, lane = tid & 63;
    int kq = lane >> 4, r = lane & 15;
    int rtg = blockIdx.x * 4 + wave;          // 0..583
    int b = rtg / (SLOTS / 16), rt = rtg % (SLOTS / 16);
    int y = blockIdx.y;                        // k-half
    unsigned short* dst = xph + (size_t)b * XPB;
    int slot = rt * 16 + r;
    int Nc = ncp[b * 2], Nkp = ncp[b * 2 + 1];
    int mend = Nkp + (N - Nc);
    bool pad = (slot >= Nc && slot < Nkp) || slot >= mend;
    int n = pad ? -1 : inv[(size_t)b * SLOTS + slot];
    #pragma unroll
    for (int kt = 0; kt < 4; ++kt) {
        int k0 = (y * 4 + kt) * 32;
        short8 v = {0, 0, 0, 0, 0, 0, 0, 0};
        if (n >= 0) {
            int gn = b * N + n;
            v = *(const short8*)&xh[(((size_t)(gn >> 4) * 8 + (k0 >> 5)) << 9)
                                    + (kq * 16 + (gn & 15)) * 8];
        }
        *(short8*)&dst[(((size_t)(rt * 8 + (k0 >> 5))) << 9) + lane * 8] = v;
    }
}

// -------- fused Q/K/V MFMA GEMM, 1-pass bf16 (R12 tiles, 8 waves/EU) -------
// __launch_bounds__(256,8) caps VGPR at 64: trades unroll/prefetch depth for
// 2x resident waves on a load-latency-bound kernel.
// z=0: Q from xn, PRE-SCALED by log2(e). z=1: K (foKI interleave).
// z=2: V^T (A = Wv^T over c, B = permuted xn over slot keys).
//      NEW: masked-key V values are row-summed into vm[] in the epilogue
//      (quad shfl-reduce + 1 atomic) instead of being stored + re-read by a
//      separate pass; masked vc region is never written.
__global__ __launch_bounds__(256, 8) void gemm_qkv(
    const unsigned short* __restrict__ xh,
    const unsigned short* __restrict__ xph,
    const unsigned short* __restrict__ Wth,
    const float* __restrict__ bq, const float* __restrict__ bk,
    const float* __restrict__ bv, const int* __restrict__ ncp,
    unsigned short* __restrict__ qb, unsigned short* __restrict__ kc,
    unsigned short* __restrict__ vc, float* __restrict__ vm)
{
    constexpr size_t WSZ = (size_t)DIM * DIM;
    int z = blockIdx.z, bx = blockIdx.x;
    int tid = threadIdx.x;
    int wave = tid >> 6, lane = tid & 63;
    int quad = lane >> 4, l16 = lane & 15;
    const unsigned short *PA, *PB;
    int arow0, brow0, b;
    if (z == 0) {
        if (bx >= 576) return;
        arow0 = (bx >> 3) * 128 + wave * 32;
        brow0 = (bx & 7) * 32;
        b = ((bx >> 3) * 128) / N;
        PA = xh; PB = Wth;
    } else if (z == 1) {
        b = bx / 152;
        int rr = bx % 152;
        arow0 = (rr >> 3) * 128 + wave * 32;
        brow0 = (rr & 7) * 32;
        if (arow0 >= SLOTS) return;
        if (arow0 >= ncp[b * 2 + 1]) return;   // masked-K region: never read
        PA = xph + (size_t)b * XPB;
        PB = Wth + WSZ;
    } else {
        if (bx >= 584) return;
        int nidx = bx % 292;
        b = nidx / 73;
        arow0 = (bx / 292) * 128 + wave * 32;   // c-dim (256)
        brow0 = (nidx % 73) * 32;               // slot keys
        PA = Wth + 2 * WSZ;
        PB = xph + (size_t)b * XPB;
    }
    f32x4 acc[2][2] = {};
    #pragma unroll
    for (int k0 = 0; k0 < DIM; k0 += 32) {
        size_t at = (((size_t)(arow0 >> 4) * 8 + (k0 >> 5)) << 9) + lane * 8;
        size_t bt = (((size_t)(brow0 >> 4) * 8 + (k0 >> 5)) << 9) + lane * 8;
        short8 a0 = *(const short8*)&PA[at];
        short8 a1 = *(const short8*)&PA[at + 4096];
        short8 b0 = *(const short8*)&PB[bt];
        short8 b1 = *(const short8*)&PB[bt + 4096];
        acc[0][0] = __builtin_amdgcn_mfma_f32_16x16x32_bf16(a0, b0, acc[0][0], 0, 0, 0);
        acc[0][1] = __builtin_amdgcn_mfma_f32_16x16x32_bf16(a0, b1, acc[0][1], 0, 0, 0);
        acc[1][0] = __builtin_amdgcn_mfma_f32_16x16x32_bf16(a1, b0, acc[1][0], 0, 0, 0);
        acc[1][1] = __builtin_amdgcn_mfma_f32_16x16x32_bf16(a1, b1, acc[1][1], 0, 0, 0);
    }
    if (z == 0) {
        int nbase = arow0 - b * N;
        #pragma unroll
        for (int j = 0; j < 2; ++j) {
            int c = brow0 + j * 16 + l16;
            int h = c >> 5, d = c & 31;
            float bs = bq[c];
            unsigned short* ob = qb + (size_t)(b * NH + h) * ((size_t)N * DH);
            #pragma unroll
            for (int i = 0; i < 2; ++i)
            #pragma unroll
            for (int r = 0; r < 4; ++r) {
                int n = nbase + i * 16 + quad * 4 + r;
                ob[foQK(n, d)] = f2bf((acc[i][j][r] + bs) * LOG2E);
            }
        }
    } else if (z == 1) {
        #pragma unroll
        for (int j = 0; j < 2; ++j) {
            int c = brow0 + j * 16 + l16;
            int h = c >> 5, d = c & 31;
            float bs = bk[c];
            unsigned short* ob = kc + (size_t)(b * NH + h) * CST;
            #pragma unroll
            for (int i = 0; i < 2; ++i)
            #pragma unroll
            for (int r = 0; r < 4; ++r) {
                int slot = arow0 + i * 16 + quad * 4 + r;
                ob[foKI(slot, d)] = f2bf(acc[i][j][r] + bs);
            }
        }
    } else {
        int Nc  = ncp[b * 2];
        int Nkp = ncp[b * 2 + 1];
        int mend = Nkp + (N - Nc);
        bool anymask = (brow0 + 32 > Nkp) && (brow0 < mend);
        #pragma unroll
        for (int i = 0; i < 2; ++i)
        #pragma unroll
        for (int r = 0; r < 4; ++r) {
            int m = arow0 + i * 16 + quad * 4 + r;
            int h = m >> 5, d = m & 31;
            float bs = bv[m];
            unsigned short* ob = vc + (size_t)(b * NH + h) * CST;
            float vsum = 0.f;
            #pragma unroll
            for (int j = 0; j < 2; ++j) {
                int key = brow0 + j * 16 + l16;
                float val = acc[i][j][r] + bs;
                if (key < Nkp) ob[foVTC(d, key)] = f2bf(val);
                else if (key < mend) vsum += val;
            }
            if (anymask) {
                vsum += __shfl_xor(vsum, 1, 64);
                vsum += __shfl_xor(vsum, 2, 64);
                vsum += __shfl_xor(vsum, 4, 64);
                vsum += __shfl_xor(vsum, 8, 64);
                if (l16 == 0) atomicAdd(&vm[(size_t)(b * NH + h) * 32 + d], vsum);
            }
        }
    }
}

// ------------- MFMA flash attention over COMPACT keys, no split ------------
// Q pre-scaled by log2e -> p = exp2(s). K tiles interleaved (foKI).
// 2-wave blocks, one 32-q-row tile per wave, full key range [0, Nkp) per
// wave -> all B*NH*(N/64) = 1152 blocks co-resident (<=8 blocks/CU), so no
// key-split partials: epilogue folds in vm (masked analytic part) and the
// 1/l normalization and writes ah directly in fo256 FragTile layout.
__global__ __launch_bounds__(128, 4) void attn_kernel(
    const unsigned short* __restrict__ Qb,
    const unsigned short* __restrict__ Kc,
    const unsigned short* __restrict__ Vc,
    const int* __restrict__ ncp,
    const float* __restrict__ vm,
    unsigned short* __restrict__ ah)
{
    __shared__ unsigned short pbuf[2 * 2 * 640];   // (wave,tile) x 16 x 40
    int tid  = threadIdx.x;
    int wave = tid >> 6, lane = tid & 63;
    int quad = lane >> 4, l16 = lane & 15;
    int bh = blockIdx.y, b = bh >> 3, h = bh & 7;

    int q0 = (blockIdx.x * 2 + wave) * 32;
    const unsigned short* Qf = Qb + (size_t)bh * ((size_t)N * DH);
    const unsigned short* Kf = Kc + (size_t)bh * CST;
    const unsigned short* Vf = Vc + (size_t)bh * CST;

    int Nc  = ncp[b * 2];
    int Nkp = ncp[b * 2 + 1];
    int kend = Nkp;

    short8 qA0 = *(const short8*)&Qf[((size_t)(q0 >> 4) << 9) + lane * 8];
    short8 qA1 = *(const short8*)&Qf[((size_t)((q0 >> 4) + 1) << 9) + lane * 8];

    f32x4 o00 = {0,0,0,0}, o01 = {0,0,0,0}, o10 = {0,0,0,0}, o11 = {0,0,0,0};
    float l0[4] = {0,0,0,0}, l1[4] = {0,0,0,0};

    unsigned short* pb0 = &pbuf[(wave * 2 + 0) * 640];
    unsigned short* pb1 = &pbuf[(wave * 2 + 1) * 640];

    short8 kB0 = *(const short8*)&Kf[lane * 8];
    short8 kB1 = *(const short8*)&Kf[512 + lane * 8];
    short8 vB0 = *(const short8*)&Vf[lane * 8];
    short8 vB1 = *(const short8*)&Vf[((size_t)(SLOTS / 32) << 9) + lane * 8];

    for (int k0 = 0; k0 < kend; k0 += 32) {
        int kn = (k0 + 32 < kend) ? k0 + 32 : 0;   // branchless wrap prefetch
        short8 nk0 = *(const short8*)&Kf[((size_t)(kn >> 4) << 9) + lane * 8];
        short8 nk1 = *(const short8*)&Kf[((size_t)((kn >> 4) + 1) << 9) + lane * 8];
        short8 nv0 = *(const short8*)&Vf[((size_t)(kn >> 5) << 9) + lane * 8];
        short8 nv1 = *(const short8*)&Vf[((size_t)((SLOTS / 32) + (kn >> 5)) << 9) + lane * 8];

        int key0 = k0 + 2 * l16;
        bool in0 = key0 < Nc;                // pad slots -> p = 0 (exact)
        bool in1 = key0 + 1 < Nc;
        f32x4 z = {0,0,0,0};
        f32x4 s00 = __builtin_amdgcn_mfma_f32_16x16x32_bf16(qA0, kB0, z, 0, 0, 0);
        f32x4 s01 = __builtin_amdgcn_mfma_f32_16x16x32_bf16(qA0, kB1, z, 0, 0, 0);
        f32x4 s10 = __builtin_amdgcn_mfma_f32_16x16x32_bf16(qA1, kB0, z, 0, 0, 0);
        f32x4 s11 = __builtin_amdgcn_mfma_f32_16x16x32_bf16(qA1, kB1, z, 0, 0, 0);
        #pragma unroll
        for (int r = 0; r < 4; ++r) {
            int row = quad * 4 + r;
            float p00 = in0 ? EXP2F(s00[r]) : 0.f;
            float p01 = in1 ? EXP2F(s01[r]) : 0.f;
            float p10 = in0 ? EXP2F(s10[r]) : 0.f;
            float p11 = in1 ? EXP2F(s11[r]) : 0.f;
            l0[r] += p00 + p01;
            l1[r] += p10 + p11;
            unsigned pk0 = (bits(p00) >> 16) | (bits(p01) & 0xffff0000u);
            unsigned pk1 = (bits(p10) >> 16) | (bits(p11) & 0xffff0000u);
            *(unsigned*)&pb0[row * 40 + 2 * l16] = pk0;
            *(unsigned*)&pb1[row * 40 + 2 * l16] = pk1;
        }
        short8 pA0 = *(const short8*)&pb0[l16 * 40 + quad * 8];
        short8 pA1 = *(const short8*)&pb1[l16 * 40 + quad * 8];
        o00 = __builtin_amdgcn_mfma_f32_16x16x32_bf16(pA0, vB0, o00, 0, 0, 0);
        o01 = __builtin_amdgcn_mfma_f32_16x16x32_bf16(pA0, vB1, o01, 0, 0, 0);
        o10 = __builtin_amdgcn_mfma_f32_16x16x32_bf16(pA1, vB0, o10, 0, 0, 0);
        o11 = __builtin_amdgcn_mfma_f32_16x16x32_bf16(pA1, vB1, o11, 0, 0, 0);

        kB0 = nk0; kB1 = nk1; vB0 = nv0; vB1 = nv1;
    }
    #pragma unroll
    for (int r = 0; r < 4; ++r) {
        #pragma unroll
        for (int off = 1; off < 16; off <<= 1) {
            l0[r] += __shfl_xor(l0[r], off, 64);
            l1[r] += __shfl_xor(l1[r], off, 64);
        }
    }
    // ---- fused combine: + masked analytic part, normalize, store fo256 ----
    float vm0 = vm[bh * 32 + l16];
    float vm1 = vm[bh * 32 + 16 + l16];
    float lext = (float)(N - Nc);            // masked cols: exp(0)=1 each
    #pragma unroll
    for (int r = 0; r < 4; ++r) {
        int row = quad * 4 + r;
        float ia = 1.f / (l0[r] + lext);
        float ib = 1.f / (l1[r] + lext);
        int ra = b * N + q0 + row;
        int rb = ra + 16;
        ah[fo256(ra, h * 32 + l16)]      = f2bf((o00[r] + vm0) * ia);
        ah[fo256(ra, h * 32 + 16 + l16)] = f2bf((o01[r] + vm1) * ia);
        ah[fo256(rb, h * 32 + l16)]      = f2bf((o10[r] + vm0) * ib);
        ah[fo256(rb, h * 32 + 16 + l16)] = f2bf((o11[r] + vm1) * ib);
    }
}

// --------- final projection GEMM (2-pass: ah*bh + ah*bl): fp32 out ---------
__global__ __launch_bounds__(256, 8) void gemm_p(
    const unsigned short* __restrict__ Ahi,
    const unsigned short* __restrict__ Wth, const unsigned short* __restrict__ Wtl,
    const float* __restrict__ bias, float* __restrict__ out)
{
    constexpr size_t WSZ = (size_t)DIM * DIM;
    const unsigned short* Bhi = Wth + 3 * WSZ;
    const unsigned short* Blo = Wtl + 3 * WSZ;
    int tid = threadIdx.x;
    int wave = tid >> 6, lane = tid & 63;
    int quad = lane >> 4, l16 = lane & 15;
    int r0 = blockIdx.y * 128 + wave * 32;
    int c0 = blockIdx.x * 16;
    f32x4 acc0 = {}, acc1 = {};
    #pragma unroll
    for (int k0 = 0; k0 < DIM; k0 += 32) {
        size_t at = (((size_t)(r0 >> 4) * 8 + (k0 >> 5)) << 9) + lane * 8;
        size_t bt = (((size_t)(c0 >> 4) * 8 + (k0 >> 5)) << 9) + lane * 8;
        short8 ah0 = *(const short8*)&Ahi[at];
        short8 ah1 = *(const short8*)&Ahi[at + 4096];
        short8 bh = *(const short8*)&Bhi[bt];
        short8 bl = *(const short8*)&Blo[bt];
        acc0 = __builtin_amdgcn_mfma_f32_16x16x32_bf16(ah0, bh, acc0, 0, 0, 0);
        acc0 = __builtin_amdgcn_mfma_f32_16x16x32_bf16(ah0, bl, acc0, 0, 0, 0);
        acc1 = __builtin_amdgcn_mfma_f32_16x16x32_bf16(ah1, bh, acc1, 0, 0, 0);
        acc1 = __builtin_amdgcn_mfma_f32_16x16x32_bf16(ah1, bl, acc1, 0, 0, 0);
    }
    int c = c0 + l16;
    float bs = bias[c];
    #pragma unroll
    for (int r = 0; r < 4; ++r) {
        int R0 = r0 + quad * 4 + r;
        out[(size_t)R0 * DIM + c] = acc0[r] + bs;
        out[(size_t)(R0 + 16) * DIM + c] = acc1[r] + bs;
    }
}

extern "C" void kernel_launch(void* const* d_in, const int* in_sizes, int n_in,
                              void* d_out, int out_size, void* d_ws, size_t ws_size,
                              hipStream_t stream)
{
    const float* x    = (const float*)d_in[0];
    const float* mask = (const float*)d_in[1];
    const float* ln_g = (const float*)d_in[2];
    const float* ln_b = (const float*)d_in[3];
    const float* Wq   = (const float*)d_in[4];
    const float* bq   = (const float*)d_in[5];
    const float* Wk   = (const float*)d_in[6];
    const float* bk   = (const float*)d_in[7];
    const float* Wv   = (const float*)d_in[8];
    const float* bv   = (const float*)d_in[9];
    const float* Wp   = (const float*)d_in[10];
    const float* bp   = (const float*)d_in[11];
    float* out = (float*)d_out;

    constexpr size_t SZ  = (size_t)M * DIM;          // 2359296
    constexpr size_t CSZ = (size_t)B * NH * CST;     // 2392064
    constexpr size_t XSZ = (size_t)B * XPB;          // 2392064
    constexpr size_t WSZ = (size_t)DIM * DIM;        // 65536
    unsigned short* p = (unsigned short*)d_ws;
    unsigned short* xh = p;  p += SZ;
    unsigned short* xph = p; p += XSZ;  // permuted xn (K/V operand)
    unsigned short* qb = p;  p += SZ;
    unsigned short* kc = p;  p += CSZ;
    unsigned short* vc = p;  p += CSZ;
    unsigned short* ah = p;  p += SZ;   // attn out hi (only)
    unsigned short* wth = p; p += 4 * WSZ;
    unsigned short* wtl = p; p += 4 * WSZ;
    float* vm = (float*)p;                       // B*NH*32 fp32
    int* inv = (int*)(vm + (size_t)B * NH * 32); // B*SLOTS
    int* ncp = inv + (size_t)B * SLOTS;

    prep_kernel<<<2564, 256, 0, stream>>>(
        x, ln_g, ln_b, xh, Wq, Wk, Wv, Wp, wth, wtl, mask, inv, ncp, vm);

    permute_x<<<dim3((B * (SLOTS / 16)) / 4, 2), 256, 0, stream>>>(
        xh, inv, ncp, xph);

    gemm_qkv<<<dim3(608, 1, 3), 256, 0, stream>>>(
        xh, xph, wth, bq, bk, bv, ncp, qb, kc, vc, vm);

    attn_kernel<<<dim3(N / 64, B * NH), 128, 0, stream>>>(
        qb, kc, vc, ncp, vm, ah);

    gemm_p<<<dim3(DIM / 16, M / 128), 256, 0, stream>>>(
        ah, wth, wtl, bp, out);
}

// Round 2
// 150.737 us; speedup vs baseline: 1.0100x; 1.0100x over previous
//
#include <hip/hip_runtime.h>
#include <math.h>

typedef __attribute__((ext_vector_type(8))) short short8;
typedef __attribute__((ext_vector_type(4))) float f32x4;

#if __has_builtin(__builtin_amdgcn_exp2f)
#define EXP2F(x) __builtin_amdgcn_exp2f(x)
#else
#define EXP2F(x) exp2f(x)
#endif

constexpr int B   = 4;
constexpr int N   = 2304;
constexpr int DIM = 256;
constexpr int NH  = 8;
constexpr int DH  = 32;
constexpr int M   = B * N;          // 9216 rows
constexpr int SLOTS = 2336;         // N + 32: kept keys + pad + masked keys
constexpr int CST = SLOTS * DH;     // per-(b,h) compact K/V element count
constexpr int XPB = SLOTS * DIM;    // per-batch permuted-xn element count
constexpr float LOG2E = 1.44269504088896f;

// float -> bf16 round-to-nearest-even, and back
__device__ inline unsigned short f2bf(float f) {
    union { float f; unsigned u; } c; c.f = f;
    unsigned u = c.u;
    u += 0x7fffu + ((u >> 16) & 1u);
    return (unsigned short)(u >> 16);
}
__device__ inline float bf2f(unsigned short h) {
    union { unsigned u; float f; } c; c.u = ((unsigned)h) << 16;
    return c.f;
}
__device__ inline unsigned bits(float f) {
    union { float f; unsigned u; } c; c.f = f; return c.u;
}

// ---- FragTile layouts: element (row r, contraction k) stored so an MFMA
// A/B-frag load (16 rows x 32 k) is ONE contiguous 1KB wave transaction.
__device__ inline size_t fo256(int r, int k) {   // [R x 256] tensors
    return ((size_t)((r >> 4) * 8 + (k >> 5)) << 9)
         + (size_t)(((((k & 31) >> 3) << 4) + (r & 15)) * 8 + (k & 7));
}
__device__ inline size_t foQK(int n, int d) {    // per-(b,h) [rows x 32]
    return ((size_t)(n >> 4) << 9)
         + (size_t)((((d >> 3) << 4) + (n & 15)) * 8 + (d & 7));
}
// K with even/odd interleave: within each 32-slot chunk, even slots fill the
// first 16-tile, odd slots the second -> packed b32 LDS writes in attn.
__device__ inline size_t foKI(int slot, int d) {
    int tile = ((slot >> 5) << 1) + (slot & 1);
    int npos = (slot & 31) >> 1;
    return ((size_t)tile << 9)
         + (size_t)((((d >> 3) << 4) + npos) * 8 + (d & 7));
}
__device__ inline size_t foVTC(int d, int key) { // per-(b,h) [32 x SLOTS]
    return ((size_t)((d >> 4) * (SLOTS / 32) + (key >> 5)) << 9)
         + (size_t)(((((key & 31) >> 3) << 4) + (d & 15)) * 8 + (key & 7));
}

// ---- setup: weight transpose/split (bx<256) | mask scan + fwd map (bx>=256)
// Scan now emits the FORWARD map fwd[b*N+n] = slot so the LN kernel can
// write the permuted xph directly (permute_x kernel eliminated). Also zeroes
// the 32 pad rows of xph per batch and the vm accumulators.
__global__ __launch_bounds__(256) void setup_kernel(
    const float* __restrict__ Wq, const float* __restrict__ Wk,
    const float* __restrict__ Wv, const float* __restrict__ Wp,
    unsigned short* __restrict__ Wth, unsigned short* __restrict__ Wtl,
    const float* __restrict__ mask, int* __restrict__ ncp,
    int* __restrict__ fwd, float* __restrict__ vm,
    unsigned short* __restrict__ xph)
{
    __shared__ float tbuf[32][33];
    __shared__ int wsum[4];
    int bx = blockIdx.x;
    int t = threadIdx.x;
    if (bx < 256) {
        // ---- weight transpose + hi/lo split (lo used only by gemm_p) ----
        int z = bx >> 6, w = bx & 63;
        const float* W = (z == 0) ? Wq : (z == 1) ? Wk : (z == 2) ? Wv : Wp;
        unsigned short* oh = Wth + (size_t)z * DIM * DIM;
        unsigned short* ol = Wtl + (size_t)z * DIM * DIM;
        int tx = t & 31, ty0 = t >> 5;
        int n0 = (w & 7) * 32, k0 = (w >> 3) * 32;
        for (int ty = ty0; ty < 32; ty += 8)
            tbuf[ty][tx] = W[(size_t)(k0 + ty) * DIM + n0 + tx];
        __syncthreads();
        for (int nn = ty0; nn < 32; nn += 8) {
            float v = tbuf[tx][nn];          // = Wt[n0+nn][k0+tx]
            unsigned short hh = f2bf(v);
            size_t o = fo256(n0 + nn, k0 + tx);
            oh[o] = hh;
            ol[o] = f2bf(v - bf2f(hh));
        }
    } else {
        // ---- mask scan (one block per batch) + fwd map + zero vm/pads ----
        int b = bx - 256;
        int wave = t >> 6, lane = t & 63;
        vm[b * 256 + t] = 0.f;               // vm is B*NH*32 = 1024 floats
        int cnt = 0;
        for (int j = t; j < N; j += 256) cnt += (mask[(size_t)b * N + j] > 0.f);
        #pragma unroll
        for (int o = 32; o > 0; o >>= 1) cnt += __shfl_down(cnt, o, 64);
        if (lane == 0) wsum[wave] = cnt;
        __syncthreads();
        int Nc = wsum[0] + wsum[1] + wsum[2] + wsum[3];
        int Nkp = (Nc + 31) & ~31;
        int mend = Nkp + (N - Nc);
        if (t == 0) { ncp[b * 2] = Nc; ncp[b * 2 + 1] = Nkp; }
        int baseK = 0;
        for (int j0 = 0; j0 < N; j0 += 256) {
            int j = j0 + t;
            bool keep = mask[(size_t)b * N + j] > 0.f;
            unsigned long long bal = __ballot(keep);
            int pos = __popcll(bal & ((1ull << lane) - 1ull));
            int wc  = __popcll(bal);
            __syncthreads();
            if (lane == 0) wsum[wave] = wc;
            __syncthreads();
            int wb = 0;
            for (int w = 0; w < wave; ++w) wb += wsum[w];
            int tot = wsum[0] + wsum[1] + wsum[2] + wsum[3];
            int keptBefore = baseK + wb + pos;
            fwd[(size_t)b * N + j] = keep ? keptBefore
                                          : Nkp + (j - keptBefore);
            baseK += tot;
        }
        // zero the (exactly 32) pad rows of xph for this batch
        int c1 = Nkp - Nc;                   // pads between kept and masked
        unsigned short* xb = xph + (size_t)b * XPB;
        for (int u = t; u < 32 * 64; u += 256) {
            int pi = u >> 6;
            int kk = (u & 63) * 4;
            int slot = (pi < c1) ? (Nc + pi) : (mend + (pi - c1));
            ushort4 z4 = {0, 0, 0, 0};
            *(ushort4*)&xb[fo256(slot, kk)] = z4;
        }
    }
}

// ---- LayerNorm: one wave per row; writes xh (row order) AND xph (slot
// order, per batch) so no separate permute pass is needed.
__global__ __launch_bounds__(256) void ln_kernel(
    const float* __restrict__ x, const float* __restrict__ g,
    const float* __restrict__ bta, const int* __restrict__ fwd,
    unsigned short* __restrict__ xh, unsigned short* __restrict__ xph)
{
    int t = threadIdx.x;
    int wave = t >> 6, lane = t & 63;
    int row = blockIdx.x * 4 + wave;
    float4 v = *(const float4*)&x[(size_t)row * DIM + lane * 4];
    float s = v.x + v.y + v.z + v.w;
    #pragma unroll
    for (int o = 32; o > 0; o >>= 1) s += __shfl_xor(s, o, 64);
    float mu = s * (1.0f / DIM);
    float d0 = v.x - mu, d1 = v.y - mu, d2 = v.z - mu, d3 = v.w - mu;
    float s2 = d0 * d0 + d1 * d1 + d2 * d2 + d3 * d3;
    #pragma unroll
    for (int o = 32; o > 0; o >>= 1) s2 += __shfl_xor(s2, o, 64);
    float r = rsqrtf(s2 * (1.0f / DIM) + 1e-5f);
    float4 gg = *(const float4*)&g[lane * 4];
    float4 bb = *(const float4*)&bta[lane * 4];
    ushort4 hi;
    hi.x = f2bf(d0 * r * gg.x + bb.x);
    hi.y = f2bf(d1 * r * gg.y + bb.y);
    hi.z = f2bf(d2 * r * gg.z + bb.z);
    hi.w = f2bf(d3 * r * gg.w + bb.w);
    *(ushort4*)&xh[fo256(row, lane * 4)] = hi;
    int b = row / N;
    int slot = fwd[row];
    *(ushort4*)&xph[(size_t)b * XPB + fo256(slot, lane * 4)] = hi;
}

// -------- fused Q/K/V MFMA GEMM, 1-pass bf16 (R12 tiles, 8 waves/EU) -------
// z=0: Q from xn, PRE-SCALED by log2(e). z=1: K (foKI interleave).
// z=2: V^T; masked-key V values row-summed into vm[] in the epilogue.
__global__ __launch_bounds__(256, 8) void gemm_qkv(
    const unsigned short* __restrict__ xh,
    const unsigned short* __restrict__ xph,
    const unsigned short* __restrict__ Wth,
    const float* __restrict__ bq, const float* __restrict__ bk,
    const float* __restrict__ bv, const int* __restrict__ ncp,
    unsigned short* __restrict__ qb, unsigned short* __restrict__ kc,
    unsigned short* __restrict__ vc, float* __restrict__ vm)
{
    constexpr size_t WSZ = (size_t)DIM * DIM;
    int z = blockIdx.z, bx = blockIdx.x;
    int tid = threadIdx.x;
    int wave = tid >> 6, lane = tid & 63;
    int quad = lane >> 4, l16 = lane & 15;
    const unsigned short *PA, *PB;
    int arow0, brow0, b;
    if (z == 0) {
        if (bx >= 576) return;
        arow0 = (bx >> 3) * 128 + wave * 32;
        brow0 = (bx & 7) * 32;
        b = ((bx >> 3) * 128) / N;
        PA = xh; PB = Wth;
    } else if (z == 1) {
        b = bx / 152;
        int rr = bx % 152;
        arow0 = (rr >> 3) * 128 + wave * 32;
        brow0 = (rr & 7) * 32;
        if (arow0 >= SLOTS) return;
        if (arow0 >= ncp[b * 2 + 1]) return;   // masked-K region: never read
        PA = xph + (size_t)b * XPB;
        PB = Wth + WSZ;
    } else {
        if (bx >= 584) return;
        int nidx = bx % 292;
        b = nidx / 73;
        arow0 = (bx / 292) * 128 + wave * 32;   // c-dim (256)
        brow0 = (nidx % 73) * 32;               // slot keys
        PA = Wth + 2 * WSZ;
        PB = xph + (size_t)b * XPB;
    }
    f32x4 acc[2][2] = {};
    #pragma unroll
    for (int k0 = 0; k0 < DIM; k0 += 32) {
        size_t at = (((size_t)(arow0 >> 4) * 8 + (k0 >> 5)) << 9) + lane * 8;
        size_t bt = (((size_t)(brow0 >> 4) * 8 + (k0 >> 5)) << 9) + lane * 8;
        short8 a0 = *(const short8*)&PA[at];
        short8 a1 = *(const short8*)&PA[at + 4096];
        short8 b0 = *(const short8*)&PB[bt];
        short8 b1 = *(const short8*)&PB[bt + 4096];
        acc[0][0] = __builtin_amdgcn_mfma_f32_16x16x32_bf16(a0, b0, acc[0][0], 0, 0, 0);
        acc[0][1] = __builtin_amdgcn_mfma_f32_16x16x32_bf16(a0, b1, acc[0][1], 0, 0, 0);
        acc[1][0] = __builtin_amdgcn_mfma_f32_16x16x32_bf16(a1, b0, acc[1][0], 0, 0, 0);
        acc[1][1] = __builtin_amdgcn_mfma_f32_16x16x32_bf16(a1, b1, acc[1][1], 0, 0, 0);
    }
    if (z == 0) {
        int nbase = arow0 - b * N;
        #pragma unroll
        for (int j = 0; j < 2; ++j) {
            int c = brow0 + j * 16 + l16;
            int h = c >> 5, d = c & 31;
            float bs = bq[c];
            unsigned short* ob = qb + (size_t)(b * NH + h) * ((size_t)N * DH);
            #pragma unroll
            for (int i = 0; i < 2; ++i)
            #pragma unroll
            for (int r = 0; r < 4; ++r) {
                int n = nbase + i * 16 + quad * 4 + r;
                ob[foQK(n, d)] = f2bf((acc[i][j][r] + bs) * LOG2E);
            }
        }
    } else if (z == 1) {
        #pragma unroll
        for (int j = 0; j < 2; ++j) {
            int c = brow0 + j * 16 + l16;
            int h = c >> 5, d = c & 31;
            float bs = bk[c];
            unsigned short* ob = kc + (size_t)(b * NH + h) * CST;
            #pragma unroll
            for (int i = 0; i < 2; ++i)
            #pragma unroll
            for (int r = 0; r < 4; ++r) {
                int slot = arow0 + i * 16 + quad * 4 + r;
                ob[foKI(slot, d)] = f2bf(acc[i][j][r] + bs);
            }
        }
    } else {
        int Nc  = ncp[b * 2];
        int Nkp = ncp[b * 2 + 1];
        int mend = Nkp + (N - Nc);
        bool anymask = (brow0 + 32 > Nkp) && (brow0 < mend);
        #pragma unroll
        for (int i = 0; i < 2; ++i)
        #pragma unroll
        for (int r = 0; r < 4; ++r) {
            int m = arow0 + i * 16 + quad * 4 + r;
            int h = m >> 5, d = m & 31;
            float bs = bv[m];
            unsigned short* ob = vc + (size_t)(b * NH + h) * CST;
            float vsum = 0.f;
            #pragma unroll
            for (int j = 0; j < 2; ++j) {
                int key = brow0 + j * 16 + l16;
                float val = acc[i][j][r] + bs;
                if (key < Nkp) ob[foVTC(d, key)] = f2bf(val);
                else if (key < mend) vsum += val;
            }
            if (anymask) {
                vsum += __shfl_xor(vsum, 1, 64);
                vsum += __shfl_xor(vsum, 2, 64);
                vsum += __shfl_xor(vsum, 4, 64);
                vsum += __shfl_xor(vsum, 8, 64);
                if (l16 == 0) atomicAdd(&vm[(size_t)(b * NH + h) * 32 + d], vsum);
            }
        }
    }
}

// ------ MFMA flash attention, IN-BLOCK key split (2 waves, no partials) ----
// Q pre-scaled by log2e -> p = exp2(s). K tiles interleaved (foKI).
// 128-thread blocks: wave kh=0/1 each cover half the key range [0,Nkp) for
// the SAME 32-q-row tile, then combine o/l through 6KB LDS (one barrier).
// 72x32 = 2304 blocks -> 4608 waves (2x R0's TLP) with zero partial-output
// HBM traffic. Epilogue folds vm (masked analytic part) + 1/l and writes ah
// directly in fo256 FragTile layout.
__global__ __launch_bounds__(128, 4) void attn_kernel(
    const unsigned short* __restrict__ Qb,
    const unsigned short* __restrict__ Kc,
    const unsigned short* __restrict__ Vc,
    const int* __restrict__ ncp,
    const float* __restrict__ vm,
    unsigned short* __restrict__ ah)
{
    __shared__ unsigned short pbuf[2 * 2 * 640];   // (wave,tile) x 16 x 40
    __shared__ float cbuf[64 * 24];                // cross-wave o/l exchange
    int tid  = threadIdx.x;
    int kh   = tid >> 6, lane = tid & 63;
    int quad = lane >> 4, l16 = lane & 15;
    int bh = blockIdx.y, b = bh >> 3, h = bh & 7;

    int q0 = blockIdx.x * 32;
    const unsigned short* Qf = Qb + (size_t)bh * ((size_t)N * DH);
    const unsigned short* Kf = Kc + (size_t)bh * CST;
    const unsigned short* Vf = Vc + (size_t)bh * CST;

    int Nc  = ncp[b * 2];
    int Nkp = ncp[b * 2 + 1];
    int chunks = Nkp >> 5;
    int kbeg = ((chunks * kh) >> 1) << 5;
    int kend = ((chunks * (kh + 1)) >> 1) << 5;

    short8 qA0 = *(const short8*)&Qf[((size_t)(q0 >> 4) << 9) + lane * 8];
    short8 qA1 = *(const short8*)&Qf[((size_t)((q0 >> 4) + 1) << 9) + lane * 8];

    f32x4 o00 = {0,0,0,0}, o01 = {0,0,0,0}, o10 = {0,0,0,0}, o11 = {0,0,0,0};
    float l0[4] = {0,0,0,0}, l1[4] = {0,0,0,0};

    unsigned short* pb0 = &pbuf[(kh * 2 + 0) * 640];
    unsigned short* pb1 = &pbuf[(kh * 2 + 1) * 640];

    short8 kB0 = *(const short8*)&Kf[((size_t)(kbeg >> 4) << 9) + lane * 8];
    short8 kB1 = *(const short8*)&Kf[((size_t)((kbeg >> 4) + 1) << 9) + lane * 8];
    short8 vB0 = *(const short8*)&Vf[((size_t)(kbeg >> 5) << 9) + lane * 8];
    short8 vB1 = *(const short8*)&Vf[((size_t)((SLOTS / 32) + (kbeg >> 5)) << 9) + lane * 8];

    for (int k0 = kbeg; k0 < kend; k0 += 32) {
        int kn = (k0 + 32 < kend) ? k0 + 32 : kbeg;   // branchless wrap prefetch
        short8 nk0 = *(const short8*)&Kf[((size_t)(kn >> 4) << 9) + lane * 8];
        short8 nk1 = *(const short8*)&Kf[((size_t)((kn >> 4) + 1) << 9) + lane * 8];
        short8 nv0 = *(const short8*)&Vf[((size_t)(kn >> 5) << 9) + lane * 8];
        short8 nv1 = *(const short8*)&Vf[((size_t)((SLOTS / 32) + (kn >> 5)) << 9) + lane * 8];

        int key0 = k0 + 2 * l16;
        bool in0 = key0 < Nc;                // pad slots -> p = 0 (exact)
        bool in1 = key0 + 1 < Nc;
        f32x4 z = {0,0,0,0};
        f32x4 s00 = __builtin_amdgcn_mfma_f32_16x16x32_bf16(qA0, kB0, z, 0, 0, 0);
        f32x4 s01 = __builtin_amdgcn_mfma_f32_16x16x32_bf16(qA0, kB1, z, 0, 0, 0);
        f32x4 s10 = __builtin_amdgcn_mfma_f32_16x16x32_bf16(qA1, kB0, z, 0, 0, 0);
        f32x4 s11 = __builtin_amdgcn_mfma_f32_16x16x32_bf16(qA1, kB1, z, 0, 0, 0);
        #pragma unroll
        for (int r = 0; r < 4; ++r) {
            int row = quad * 4 + r;
            float p00 = in0 ? EXP2F(s00[r]) : 0.f;
            float p01 = in1 ? EXP2F(s01[r]) : 0.f;
            float p10 = in0 ? EXP2F(s10[r]) : 0.f;
            float p11 = in1 ? EXP2F(s11[r]) : 0.f;
            l0[r] += p00 + p01;
            l1[r] += p10 + p11;
            unsigned pk0 = (bits(p00) >> 16) | (bits(p01) & 0xffff0000u);
            unsigned pk1 = (bits(p10) >> 16) | (bits(p11) & 0xffff0000u);
            *(unsigned*)&pb0[row * 40 + 2 * l16] = pk0;
            *(unsigned*)&pb1[row * 40 + 2 * l16] = pk1;
        }
        short8 pA0 = *(const short8*)&pb0[l16 * 40 + quad * 8];
        short8 pA1 = *(const short8*)&pb1[l16 * 40 + quad * 8];
        o00 = __builtin_amdgcn_mfma_f32_16x16x32_bf16(pA0, vB0, o00, 0, 0, 0);
        o01 = __builtin_amdgcn_mfma_f32_16x16x32_bf16(pA0, vB1, o01, 0, 0, 0);
        o10 = __builtin_amdgcn_mfma_f32_16x16x32_bf16(pA1, vB0, o10, 0, 0, 0);
        o11 = __builtin_amdgcn_mfma_f32_16x16x32_bf16(pA1, vB1, o11, 0, 0, 0);

        kB0 = nk0; kB1 = nk1; vB0 = nv0; vB1 = nv1;
    }
    #pragma unroll
    for (int r = 0; r < 4; ++r) {
        #pragma unroll
        for (int off = 1; off < 16; off <<= 1) {
            l0[r] += __shfl_xor(l0[r], off, 64);
            l1[r] += __shfl_xor(l1[r], off, 64);
        }
    }
    // ---- cross-wave combine through LDS ----
    if (kh == 1) {
        float* cb = &cbuf[lane * 24];
        *(f32x4*)&cb[0]  = o00;
        *(f32x4*)&cb[4]  = o01;
        *(f32x4*)&cb[8]  = o10;
        *(f32x4*)&cb[12] = o11;
        #pragma unroll
        for (int r = 0; r < 4; ++r) { cb[16 + r] = l0[r]; cb[20 + r] = l1[r]; }
    }
    __syncthreads();
    if (kh == 1) return;
    {
        float* cb = &cbuf[lane * 24];
        o00 += *(f32x4*)&cb[0];
        o01 += *(f32x4*)&cb[4];
        o10 += *(f32x4*)&cb[8];
        o11 += *(f32x4*)&cb[12];
        #pragma unroll
        for (int r = 0; r < 4; ++r) { l0[r] += cb[16 + r]; l1[r] += cb[20 + r]; }
    }
    // ---- fused combine: + masked analytic part, normalize, store fo256 ----
    float vm0 = vm[bh * 32 + l16];
    float vm1 = vm[bh * 32 + 16 + l16];
    float lext = (float)(N - Nc);            // masked cols: exp(0)=1 each
    #pragma unroll
    for (int r = 0; r < 4; ++r) {
        int row = quad * 4 + r;
        float ia = 1.f / (l0[r] + lext);
        float ib = 1.f / (l1[r] + lext);
        int ra = b * N + q0 + row;
        int rb = ra + 16;
        ah[fo256(ra, h * 32 + l16)]      = f2bf((o00[r] + vm0) * ia);
        ah[fo256(ra, h * 32 + 16 + l16)] = f2bf((o01[r] + vm1) * ia);
        ah[fo256(rb, h * 32 + l16)]      = f2bf((o10[r] + vm0) * ib);
        ah[fo256(rb, h * 32 + 16 + l16)] = f2bf((o11[r] + vm1) * ib);
    }
}

// --------- final projection GEMM (2-pass: ah*bh + ah*bl): fp32 out ---------
__global__ __launch_bounds__(256, 8) void gemm_p(
    const unsigned short* __restrict__ Ahi,
    const unsigned short* __restrict__ Wth, const unsigned short* __restrict__ Wtl,
    const float* __restrict__ bias, float* __restrict__ out)
{
    constexpr size_t WSZ = (size_t)DIM * DIM;
    const unsigned short* Bhi = Wth + 3 * WSZ;
    const unsigned short* Blo = Wtl + 3 * WSZ;
    int tid = threadIdx.x;
    int wave = tid >> 6, lane = tid & 63;
    int quad = lane >> 4, l16 = lane & 15;
    int r0 = blockIdx.y * 128 + wave * 32;
    int c0 = blockIdx.x * 16;
    f32x4 acc0 = {}, acc1 = {};
    #pragma unroll
    for (int k0 = 0; k0 < DIM; k0 += 32) {
        size_t at = (((size_t)(r0 >> 4) * 8 + (k0 >> 5)) << 9) + lane * 8;
        size_t bt = (((size_t)(c0 >> 4) * 8 + (k0 >> 5)) << 9) + lane * 8;
        short8 ah0 = *(const short8*)&Ahi[at];
        short8 ah1 = *(const short8*)&Ahi[at + 4096];
        short8 bh = *(const short8*)&Bhi[bt];
        short8 bl = *(const short8*)&Blo[bt];
        acc0 = __builtin_amdgcn_mfma_f32_16x16x32_bf16(ah0, bh, acc0, 0, 0, 0);
        acc0 = __builtin_amdgcn_mfma_f32_16x16x32_bf16(ah0, bl, acc0, 0, 0, 0);
        acc1 = __builtin_amdgcn_mfma_f32_16x16x32_bf16(ah1, bh, acc1, 0, 0, 0);
        acc1 = __builtin_amdgcn_mfma_f32_16x16x32_bf16(ah1, bl, acc1, 0, 0, 0);
    }
    int c = c0 + l16;
    float bs = bias[c];
    #pragma unroll
    for (int r = 0; r < 4; ++r) {
        int R0 = r0 + quad * 4 + r;
        out[(size_t)R0 * DIM + c] = acc0[r] + bs;
        out[(size_t)(R0 + 16) * DIM + c] = acc1[r] + bs;
    }
}

extern "C" void kernel_launch(void* const* d_in, const int* in_sizes, int n_in,
                              void* d_out, int out_size, void* d_ws, size_t ws_size,
                              hipStream_t stream)
{
    const float* x    = (const float*)d_in[0];
    const float* mask = (const float*)d_in[1];
    const float* ln_g = (const float*)d_in[2];
    const float* ln_b = (const float*)d_in[3];
    const float* Wq   = (const float*)d_in[4];
    const float* bq   = (const float*)d_in[5];
    const float* Wk   = (const float*)d_in[6];
    const float* bk   = (const float*)d_in[7];
    const float* Wv   = (const float*)d_in[8];
    const float* bv   = (const float*)d_in[9];
    const float* Wp   = (const float*)d_in[10];
    const float* bp   = (const float*)d_in[11];
    float* out = (float*)d_out;

    constexpr size_t SZ  = (size_t)M * DIM;          // 2359296
    constexpr size_t CSZ = (size_t)B * NH * CST;     // 2392064
    constexpr size_t XSZ = (size_t)B * XPB;          // 2392064
    constexpr size_t WSZ = (size_t)DIM * DIM;        // 65536
    unsigned short* p = (unsigned short*)d_ws;
    unsigned short* xh = p;  p += SZ;
    unsigned short* xph = p; p += XSZ;  // permuted xn (K/V operand)
    unsigned short* qb = p;  p += SZ;
    unsigned short* kc = p;  p += CSZ;
    unsigned short* vc = p;  p += CSZ;
    unsigned short* ah = p;  p += SZ;   // attn out hi (only)
    unsigned short* wth = p; p += 4 * WSZ;
    unsigned short* wtl = p; p += 4 * WSZ;
    float* vm = (float*)p;                       // B*NH*32 fp32
    int* ncp = (int*)(vm + (size_t)B * NH * 32); // B*2
    int* fwd = ncp + 2 * B;                      // M ints

    setup_kernel<<<260, 256, 0, stream>>>(
        Wq, Wk, Wv, Wp, wth, wtl, mask, ncp, fwd, vm, xph);

    ln_kernel<<<2304, 256, 0, stream>>>(
        x, ln_g, ln_b, fwd, xh, xph);

    gemm_qkv<<<dim3(608, 1, 3), 256, 0, stream>>>(
        xh, xph, wth, bq, bk, bv, ncp, qb, kc, vc, vm);

    attn_kernel<<<dim3(N / 32, B * NH), 128, 0, stream>>>(
        qb, kc, vc, ncp, vm, ah);

    gemm_p<<<dim3(DIM / 16, M / 128), 256, 0, stream>>>(
        ah, wth, wtl, bp, out);
}

// Round 4
// 148.084 us; speedup vs baseline: 1.0281x; 1.0179x over previous
//
#include <hip/hip_runtime.h>
#include <math.h>

typedef __attribute__((ext_vector_type(8))) short short8;
typedef __attribute__((ext_vector_type(4))) float f32x4;

#if __has_builtin(__builtin_amdgcn_exp2f)
#define EXP2F(x) __builtin_amdgcn_exp2f(x)
#else
#define EXP2F(x) exp2f(x)
#endif

constexpr int B   = 4;
constexpr int N   = 2304;
constexpr int DIM = 256;
constexpr int NH  = 8;
constexpr int DH  = 32;
constexpr int M   = B * N;          // 9216 rows
constexpr int SLOTS = 2336;         // N + 32: kept keys + pad + masked keys
constexpr int CST = SLOTS * DH;     // per-(b,h) compact K/V element count
constexpr int XPB = SLOTS * DIM;    // per-batch permuted-xn element count
constexpr float LOG2E = 1.44269504088896f;

// float -> bf16 round-to-nearest-even, and back
__device__ inline unsigned short f2bf(float f) {
    union { float f; unsigned u; } c; c.f = f;
    unsigned u = c.u;
    u += 0x7fffu + ((u >> 16) & 1u);
    return (unsigned short)(u >> 16);
}
__device__ inline float bf2f(unsigned short h) {
    union { unsigned u; float f; } c; c.u = ((unsigned)h) << 16;
    return c.f;
}
__device__ inline unsigned bits(float f) {
    union { float f; unsigned u; } c; c.f = f; return c.u;
}

// ---- FragTile layouts: element (row r, contraction k) stored so an MFMA
// A/B-frag load (16 rows x 32 k) is ONE contiguous 1KB wave transaction.
__device__ inline size_t fo256(int r, int k) {   // [R x 256] tensors
    return ((size_t)((r >> 4) * 8 + (k >> 5)) << 9)
         + (size_t)(((((k & 31) >> 3) << 4) + (r & 15)) * 8 + (k & 7));
}
__device__ inline size_t foQK(int n, int d) {    // per-(b,h) [rows x 32]
    return ((size_t)(n >> 4) << 9)
         + (size_t)((((d >> 3) << 4) + (n & 15)) * 8 + (d & 7));
}
// K with even/odd interleave: within each 32-slot chunk, even slots fill the
// first 16-tile, odd slots the second -> packed b32 LDS writes in attn.
__device__ inline size_t foKI(int slot, int d) {
    int tile = ((slot >> 5) << 1) + (slot & 1);
    int npos = (slot & 31) >> 1;
    return ((size_t)tile << 9)
         + (size_t)((((d >> 3) << 4) + npos) * 8 + (d & 7));
}
__device__ inline size_t foVTC(int d, int key) { // per-(b,h) [32 x SLOTS]
    return ((size_t)((d >> 4) * (SLOTS / 32) + (key >> 5)) << 9)
         + (size_t)(((((key & 31) >> 3) << 4) + (d & 15)) * 8 + (key & 7));
}

// ---- mask scan, TWO-PASS (one barrier): per-(chunk,wave) ballots cached in
// LDS, then prefix computed per-thread. Emits fwd map, ncp, zeroes vm and
// the 32 pad rows of xph per batch. 4 blocks (one per batch).
__global__ __launch_bounds__(256) void scan_kernel(
    const float* __restrict__ mask, int* __restrict__ ncp,
    int* __restrict__ fwd, float* __restrict__ vm,
    unsigned short* __restrict__ xph)
{
    __shared__ int wcnt[9][4];
    __shared__ unsigned long long wbal[9][4];
    int b = blockIdx.x;
    int t = threadIdx.x;
    int wave = t >> 6, lane = t & 63;
    vm[b * 256 + t] = 0.f;                   // vm is B*NH*32 = 1024 floats
    // pass A: ballots
    #pragma unroll
    for (int c = 0; c < 9; ++c) {
        int j = c * 256 + t;
        bool keep = mask[(size_t)b * N + j] > 0.f;
        unsigned long long bal = __ballot(keep);
        if (lane == 0) { wcnt[c][wave] = __popcll(bal); wbal[c][wave] = bal; }
    }
    __syncthreads();
    int Nc = 0;
    #pragma unroll
    for (int c = 0; c < 9; ++c)
        Nc += wcnt[c][0] + wcnt[c][1] + wcnt[c][2] + wcnt[c][3];
    int Nkp = (Nc + 31) & ~31;
    int mend = Nkp + (N - Nc);
    if (t == 0) { ncp[b * 2] = Nc; ncp[b * 2 + 1] = Nkp; }
    // pass B: prefix + fwd writes (no barriers)
    int base = 0;
    #pragma unroll
    for (int c = 0; c < 9; ++c) {
        int wb = base;
        for (int w = 0; w < wave; ++w) wb += wcnt[c][w];
        unsigned long long bal = wbal[c][wave];
        bool keep = (bal >> lane) & 1ull;
        int pos = __popcll(bal & ((1ull << lane) - 1ull));
        int keptBefore = wb + pos;
        int j = c * 256 + t;
        fwd[(size_t)b * N + j] = keep ? keptBefore : Nkp + (j - keptBefore);
        base += wcnt[c][0] + wcnt[c][1] + wcnt[c][2] + wcnt[c][3];
    }
    // zero the (exactly 32) pad rows of xph for this batch
    int c1 = Nkp - Nc;                       // pads between kept and masked
    unsigned short* xb = xph + (size_t)b * XPB;
    for (int u = t; u < 32 * 64; u += 256) {
        int pi = u >> 6;
        int kk = (u & 63) * 4;
        int slot = (pi < c1) ? (Nc + pi) : (mend + (pi - c1));
        ushort4 z4 = {0, 0, 0, 0};
        *(ushort4*)&xb[fo256(slot, kk)] = z4;
    }
}

// ---- prep2: weight transpose/split (bx<256) | LayerNorm -> xh + xph ------
__global__ __launch_bounds__(256) void prep2(
    const float* __restrict__ x, const float* __restrict__ g,
    const float* __restrict__ bta, const int* __restrict__ fwd,
    const float* __restrict__ Wq, const float* __restrict__ Wk,
    const float* __restrict__ Wv, const float* __restrict__ Wp,
    unsigned short* __restrict__ Wth, unsigned short* __restrict__ Wtl,
    unsigned short* __restrict__ xh, unsigned short* __restrict__ xph)
{
    __shared__ float tbuf[32][33];
    int bx = blockIdx.x;
    int t = threadIdx.x;
    if (bx < 256) {
        // ---- weight transpose + hi/lo split (lo used only by gemm_p) ----
        int z = bx >> 6, w = bx & 63;
        const float* W = (z == 0) ? Wq : (z == 1) ? Wk : (z == 2) ? Wv : Wp;
        unsigned short* oh = Wth + (size_t)z * DIM * DIM;
        unsigned short* ol = Wtl + (size_t)z * DIM * DIM;
        int tx = t & 31, ty0 = t >> 5;
        int n0 = (w & 7) * 32, k0 = (w >> 3) * 32;
        for (int ty = ty0; ty < 32; ty += 8)
            tbuf[ty][tx] = W[(size_t)(k0 + ty) * DIM + n0 + tx];
        __syncthreads();
        for (int nn = ty0; nn < 32; nn += 8) {
            float v = tbuf[tx][nn];          // = Wt[n0+nn][k0+tx]
            unsigned short hh = f2bf(v);
            size_t o = fo256(n0 + nn, k0 + tx);
            oh[o] = hh;
            ol[o] = f2bf(v - bf2f(hh));
        }
    } else {
        // ---- LayerNorm, one wave per row; writes xh AND permuted xph ----
        int wave = t >> 6, lane = t & 63;
        int row = (bx - 256) * 4 + wave;
        float4 v = *(const float4*)&x[(size_t)row * DIM + lane * 4];
        float s = v.x + v.y + v.z + v.w;
        #pragma unroll
        for (int o = 32; o > 0; o >>= 1) s += __shfl_xor(s, o, 64);
        float mu = s * (1.0f / DIM);
        float d0 = v.x - mu, d1 = v.y - mu, d2 = v.z - mu, d3 = v.w - mu;
        float s2 = d0 * d0 + d1 * d1 + d2 * d2 + d3 * d3;
        #pragma unroll
        for (int o = 32; o > 0; o >>= 1) s2 += __shfl_xor(s2, o, 64);
        float r = rsqrtf(s2 * (1.0f / DIM) + 1e-5f);
        float4 gg = *(const float4*)&g[lane * 4];
        float4 bb = *(const float4*)&bta[lane * 4];
        ushort4 hi;
        hi.x = f2bf(d0 * r * gg.x + bb.x);
        hi.y = f2bf(d1 * r * gg.y + bb.y);
        hi.z = f2bf(d2 * r * gg.z + bb.z);
        hi.w = f2bf(d3 * r * gg.w + bb.w);
        *(ushort4*)&xh[fo256(row, lane * 4)] = hi;
        int b = row / N;
        int slot = fwd[row];
        *(ushort4*)&xph[(size_t)b * XPB + fo256(slot, lane * 4)] = hi;
    }
}

// -------- fused Q/K/V MFMA GEMM, 1-pass bf16 (R12 tiles, 8 waves/EU) -------
// z=0: Q from xn, PRE-SCALED by log2(e). z=1: K (foKI interleave).
// z=2: V^T; masked-key V values row-summed into vm[] in the epilogue.
__global__ __launch_bounds__(256, 8) void gemm_qkv(
    const unsigned short* __restrict__ xh,
    const unsigned short* __restrict__ xph,
    const unsigned short* __restrict__ Wth,
    const float* __restrict__ bq, const float* __restrict__ bk,
    const float* __restrict__ bv, const int* __restrict__ ncp,
    unsigned short* __restrict__ qb, unsigned short* __restrict__ kc,
    unsigned short* __restrict__ vc, float* __restrict__ vm)
{
    constexpr size_t WSZ = (size_t)DIM * DIM;
    int z = blockIdx.z, bx = blockIdx.x;
    int tid = threadIdx.x;
    int wave = tid >> 6, lane = tid & 63;
    int quad = lane >> 4, l16 = lane & 15;
    const unsigned short *PA, *PB;
    int arow0, brow0, b;
    if (z == 0) {
        if (bx >= 576) return;
        arow0 = (bx >> 3) * 128 + wave * 32;
        brow0 = (bx & 7) * 32;
        b = ((bx >> 3) * 128) / N;
        PA = xh; PB = Wth;
    } else if (z == 1) {
        b = bx / 152;
        int rr = bx % 152;
        arow0 = (rr >> 3) * 128 + wave * 32;
        brow0 = (rr & 7) * 32;
        if (arow0 >= SLOTS) return;
        if (arow0 >= ncp[b * 2 + 1]) return;   // masked-K region: never read
        PA = xph + (size_t)b * XPB;
        PB = Wth + WSZ;
    } else {
        if (bx >= 584) return;
        int nidx = bx % 292;
        b = nidx / 73;
        arow0 = (bx / 292) * 128 + wave * 32;   // c-dim (256)
        brow0 = (nidx % 73) * 32;               // slot keys
        PA = Wth + 2 * WSZ;
        PB = xph + (size_t)b * XPB;
    }
    f32x4 acc[2][2] = {};
    #pragma unroll
    for (int k0 = 0; k0 < DIM; k0 += 32) {
        size_t at = (((size_t)(arow0 >> 4) * 8 + (k0 >> 5)) << 9) + lane * 8;
        size_t bt = (((size_t)(brow0 >> 4) * 8 + (k0 >> 5)) << 9) + lane * 8;
        short8 a0 = *(const short8*)&PA[at];
        short8 a1 = *(const short8*)&PA[at + 4096];
        short8 b0 = *(const short8*)&PB[bt];
        short8 b1 = *(const short8*)&PB[bt + 4096];
        acc[0][0] = __builtin_amdgcn_mfma_f32_16x16x32_bf16(a0, b0, acc[0][0], 0, 0, 0);
        acc[0][1] = __builtin_amdgcn_mfma_f32_16x16x32_bf16(a0, b1, acc[0][1], 0, 0, 0);
        acc[1][0] = __builtin_amdgcn_mfma_f32_16x16x32_bf16(a1, b0, acc[1][0], 0, 0, 0);
        acc[1][1] = __builtin_amdgcn_mfma_f32_16x16x32_bf16(a1, b1, acc[1][1], 0, 0, 0);
    }
    if (z == 0) {
        int nbase = arow0 - b * N;
        #pragma unroll
        for (int j = 0; j < 2; ++j) {
            int c = brow0 + j * 16 + l16;
            int h = c >> 5, d = c & 31;
            float bs = bq[c];
            unsigned short* ob = qb + (size_t)(b * NH + h) * ((size_t)N * DH);
            #pragma unroll
            for (int i = 0; i < 2; ++i)
            #pragma unroll
            for (int r = 0; r < 4; ++r) {
                int n = nbase + i * 16 + quad * 4 + r;
                ob[foQK(n, d)] = f2bf((acc[i][j][r] + bs) * LOG2E);
            }
        }
    } else if (z == 1) {
        #pragma unroll
        for (int j = 0; j < 2; ++j) {
            int c = brow0 + j * 16 + l16;
            int h = c >> 5, d = c & 31;
            float bs = bk[c];
            unsigned short* ob = kc + (size_t)(b * NH + h) * CST;
            #pragma unroll
            for (int i = 0; i < 2; ++i)
            #pragma unroll
            for (int r = 0; r < 4; ++r) {
                int slot = arow0 + i * 16 + quad * 4 + r;
                ob[foKI(slot, d)] = f2bf(acc[i][j][r] + bs);
            }
        }
    } else {
        int Nc  = ncp[b * 2];
        int Nkp = ncp[b * 2 + 1];
        int mend = Nkp + (N - Nc);
        bool anymask = (brow0 + 32 > Nkp) && (brow0 < mend);
        #pragma unroll
        for (int i = 0; i < 2; ++i)
        #pragma unroll
        for (int r = 0; r < 4; ++r) {
            int m = arow0 + i * 16 + quad * 4 + r;
            int h = m >> 5, d = m & 31;
            float bs = bv[m];
            unsigned short* ob = vc + (size_t)(b * NH + h) * CST;
            float vsum = 0.f;
            #pragma unroll
            for (int j = 0; j < 2; ++j) {
                int key = brow0 + j * 16 + l16;
                float val = acc[i][j][r] + bs;
                if (key < Nkp) ob[foVTC(d, key)] = f2bf(val);
                else if (key < mend) vsum += val;
            }
            if (anymask) {
                vsum += __shfl_xor(vsum, 1, 64);
                vsum += __shfl_xor(vsum, 2, 64);
                vsum += __shfl_xor(vsum, 4, 64);
                vsum += __shfl_xor(vsum, 8, 64);
                if (l16 == 0) atomicAdd(&vm[(size_t)(b * NH + h) * 32 + d], vsum);
            }
        }
    }
}

// ------ MFMA flash attention, IN-BLOCK key split (2 waves, no partials) ----
// Q pre-scaled by log2e -> p = exp2(s). K tiles interleaved (foKI).
// 128-thread blocks: wave kh=0/1 each cover half the key range [0,Nkp) for
// the SAME 32-q-row tile, then combine o/l through 6KB LDS (one barrier).
// Epilogue folds vm (masked analytic part) + 1/l and writes ah directly in
// fo256 FragTile layout.
__global__ __launch_bounds__(128, 4) void attn_kernel(
    const unsigned short* __restrict__ Qb,
    const unsigned short* __restrict__ Kc,
    const unsigned short* __restrict__ Vc,
    const int* __restrict__ ncp,
    const float* __restrict__ vm,
    unsigned short* __restrict__ ah)
{
    __shared__ unsigned short pbuf[2 * 2 * 640];   // (wave,tile) x 16 x 40
    __shared__ float cbuf[64 * 24];                // cross-wave o/l exchange
    int tid  = threadIdx.x;
    int kh   = tid >> 6, lane = tid & 63;
    int quad = lane >> 4, l16 = lane & 15;
    int bh = blockIdx.y, b = bh >> 3, h = bh & 7;

    int q0 = blockIdx.x * 32;
    const unsigned short* Qf = Qb + (size_t)bh * ((size_t)N * DH);
    const unsigned short* Kf = Kc + (size_t)bh * CST;
    const unsigned short* Vf = Vc + (size_t)bh * CST;

    int Nc  = ncp[b * 2];
    int Nkp = ncp[b * 2 + 1];
    int chunks = Nkp >> 5;
    int kbeg = ((chunks * kh) >> 1) << 5;
    int kend = ((chunks * (kh + 1)) >> 1) << 5;

    short8 qA0 = *(const short8*)&Qf[((size_t)(q0 >> 4) << 9) + lane * 8];
    short8 qA1 = *(const short8*)&Qf[((size_t)((q0 >> 4) + 1) << 9) + lane * 8];

    f32x4 o00 = {0,0,0,0}, o01 = {0,0,0,0}, o10 = {0,0,0,0}, o11 = {0,0,0,0};
    float l0[4] = {0,0,0,0}, l1[4] = {0,0,0,0};

    unsigned short* pb0 = &pbuf[(kh * 2 + 0) * 640];
    unsigned short* pb1 = &pbuf[(kh * 2 + 1) * 640];

    short8 kB0 = *(const short8*)&Kf[((size_t)(kbeg >> 4) << 9) + lane * 8];
    short8 kB1 = *(const short8*)&Kf[((size_t)((kbeg >> 4) + 1) << 9) + lane * 8];
    short8 vB0 = *(const short8*)&Vf[((size_t)(kbeg >> 5) << 9) + lane * 8];
    short8 vB1 = *(const short8*)&Vf[((size_t)((SLOTS / 32) + (kbeg >> 5)) << 9) + lane * 8];

    for (int k0 = kbeg; k0 < kend; k0 += 32) {
        int kn = (k0 + 32 < kend) ? k0 + 32 : kbeg;   // branchless wrap prefetch
        short8 nk0 = *(const short8*)&Kf[((size_t)(kn >> 4) << 9) + lane * 8];
        short8 nk1 = *(const short8*)&Kf[((size_t)((kn >> 4) + 1) << 9) + lane * 8];
        short8 nv0 = *(const short8*)&Vf[((size_t)(kn >> 5) << 9) + lane * 8];
        short8 nv1 = *(const short8*)&Vf[((size_t)((SLOTS / 32) + (kn >> 5)) << 9) + lane * 8];

        int key0 = k0 + 2 * l16;
        bool in0 = key0 < Nc;                // pad slots -> p = 0 (exact)
        bool in1 = key0 + 1 < Nc;
        f32x4 z = {0,0,0,0};
        f32x4 s00 = __builtin_amdgcn_mfma_f32_16x16x32_bf16(qA0, kB0, z, 0, 0, 0);
        f32x4 s01 = __builtin_amdgcn_mfma_f32_16x16x32_bf16(qA0, kB1, z, 0, 0, 0);
        f32x4 s10 = __builtin_amdgcn_mfma_f32_16x16x32_bf16(qA1, kB0, z, 0, 0, 0);
        f32x4 s11 = __builtin_amdgcn_mfma_f32_16x16x32_bf16(qA1, kB1, z, 0, 0, 0);
        #pragma unroll
        for (int r = 0; r < 4; ++r) {
            int row = quad * 4 + r;
            float p00 = in0 ? EXP2F(s00[r]) : 0.f;
            float p01 = in1 ? EXP2F(s01[r]) : 0.f;
            float p10 = in0 ? EXP2F(s10[r]) : 0.f;
            float p11 = in1 ? EXP2F(s11[r]) : 0.f;
            l0[r] += p00 + p01;
            l1[r] += p10 + p11;
            unsigned pk0 = (bits(p00) >> 16) | (bits(p01) & 0xffff0000u);
            unsigned pk1 = (bits(p10) >> 16) | (bits(p11) & 0xffff0000u);
            *(unsigned*)&pb0[row * 40 + 2 * l16] = pk0;
            *(unsigned*)&pb1[row * 40 + 2 * l16] = pk1;
        }
        short8 pA0 = *(const short8*)&pb0[l16 * 40 + quad * 8];
        short8 pA1 = *(const short8*)&pb1[l16 * 40 + quad * 8];
        o00 = __builtin_amdgcn_mfma_f32_16x16x32_bf16(pA0, vB0, o00, 0, 0, 0);
        o01 = __builtin_amdgcn_mfma_f32_16x16x32_bf16(pA0, vB1, o01, 0, 0, 0);
        o10 = __builtin_amdgcn_mfma_f32_16x16x32_bf16(pA1, vB0, o10, 0, 0, 0);
        o11 = __builtin_amdgcn_mfma_f32_16x16x32_bf16(pA1, vB1, o11, 0, 0, 0);

        kB0 = nk0; kB1 = nk1; vB0 = nv0; vB1 = nv1;
    }
    #pragma unroll
    for (int r = 0; r < 4; ++r) {
        #pragma unroll
        for (int off = 1; off < 16; off <<= 1) {
            l0[r] += __shfl_xor(l0[r], off, 64);
            l1[r] += __shfl_xor(l1[r], off, 64);
        }
    }
    // ---- cross-wave combine through LDS ----
    if (kh == 1) {
        float* cb = &cbuf[lane * 24];
        *(f32x4*)&cb[0]  = o00;
        *(f32x4*)&cb[4]  = o01;
        *(f32x4*)&cb[8]  = o10;
        *(f32x4*)&cb[12] = o11;
        #pragma unroll
        for (int r = 0; r < 4; ++r) { cb[16 + r] = l0[r]; cb[20 + r] = l1[r]; }
    }
    __syncthreads();
    if (kh == 1) return;
    {
        float* cb = &cbuf[lane * 24];
        o00 += *(f32x4*)&cb[0];
        o01 += *(f32x4*)&cb[4];
        o10 += *(f32x4*)&cb[8];
        o11 += *(f32x4*)&cb[12];
        #pragma unroll
        for (int r = 0; r < 4; ++r) { l0[r] += cb[16 + r]; l1[r] += cb[20 + r]; }
    }
    // ---- fused combine: + masked analytic part, normalize, store fo256 ----
    float vm0 = vm[bh * 32 + l16];
    float vm1 = vm[bh * 32 + 16 + l16];
    float lext = (float)(N - Nc);            // masked cols: exp(0)=1 each
    #pragma unroll
    for (int r = 0; r < 4; ++r) {
        int row = quad * 4 + r;
        float ia = 1.f / (l0[r] + lext);
        float ib = 1.f / (l1[r] + lext);
        int ra = b * N + q0 + row;
        int rb = ra + 16;
        ah[fo256(ra, h * 32 + l16)]      = f2bf((o00[r] + vm0) * ia);
        ah[fo256(ra, h * 32 + 16 + l16)] = f2bf((o01[r] + vm1) * ia);
        ah[fo256(rb, h * 32 + l16)]      = f2bf((o10[r] + vm0) * ib);
        ah[fo256(rb, h * 32 + 16 + l16)] = f2bf((o11[r] + vm1) * ib);
    }
}

// --------- final projection GEMM (2-pass: ah*bh + ah*bl): fp32 out ---------
__global__ __launch_bounds__(256, 8) void gemm_p(
    const unsigned short* __restrict__ Ahi,
    const unsigned short* __restrict__ Wth, const unsigned short* __restrict__ Wtl,
    const float* __restrict__ bias, float* __restrict__ out)
{
    constexpr size_t WSZ = (size_t)DIM * DIM;
    const unsigned short* Bhi = Wth + 3 * WSZ;
    const unsigned short* Blo = Wtl + 3 * WSZ;
    int tid = threadIdx.x;
    int wave = tid >> 6, lane = tid & 63;
    int quad = lane >> 4, l16 = lane & 15;
    int r0 = blockIdx.y * 128 + wave * 32;
    int c0 = blockIdx.x * 16;
    f32x4 acc0 = {}, acc1 = {};
    #pragma unroll
    for (int k0 = 0; k0 < DIM; k0 += 32) {
        size_t at = (((size_t)(r0 >> 4) * 8 + (k0 >> 5)) << 9) + lane * 8;
        size_t bt = (((size_t)(c0 >> 4) * 8 + (k0 >> 5)) << 9) + lane * 8;
        short8 ah0 = *(const short8*)&Ahi[at];
        short8 ah1 = *(const short8*)&Ahi[at + 4096];
        short8 bh = *(const short8*)&Bhi[bt];
        short8 bl = *(const short8*)&Blo[bt];
        acc0 = __builtin_amdgcn_mfma_f32_16x16x32_bf16(ah0, bh, acc0, 0, 0, 0);
        acc0 = __builtin_amdgcn_mfma_f32_16x16x32_bf16(ah0, bl, acc0, 0, 0, 0);
        acc1 = __builtin_amdgcn_mfma_f32_16x16x32_bf16(ah1, bh, acc1, 0, 0, 0);
        acc1 = __builtin_amdgcn_mfma_f32_16x16x32_bf16(ah1, bl, acc1, 0, 0, 0);
    }
    int c = c0 + l16;
    float bs = bias[c];
    #pragma unroll
    for (int r = 0; r < 4; ++r) {
        int R0 = r0 + quad * 4 + r;
        out[(size_t)R0 * DIM + c] = acc0[r] + bs;
        out[(size_t)(R0 + 16) * DIM + c] = acc1[r] + bs;
    }
}

extern "C" void kernel_launch(void* const* d_in, const int* in_sizes, int n_in,
                              void* d_out, int out_size, void* d_ws, size_t ws_size,
                              hipStream_t stream)
{
    const float* x    = (const float*)d_in[0];
    const float* mask = (const float*)d_in[1];
    const float* ln_g = (const float*)d_in[2];
    const float* ln_b = (const float*)d_in[3];
    const float* Wq   = (const float*)d_in[4];
    const float* bq   = (const float*)d_in[5];
    const float* Wk   = (const float*)d_in[6];
    const float* bk   = (const float*)d_in[7];
    const float* Wv   = (const float*)d_in[8];
    const float* bv   = (const float*)d_in[9];
    const float* Wp   = (const float*)d_in[10];
    const float* bp   = (const float*)d_in[11];
    float* out = (float*)d_out;

    constexpr size_t SZ  = (size_t)M * DIM;          // 2359296
    constexpr size_t CSZ = (size_t)B * NH * CST;     // 2392064
    constexpr size_t XSZ = (size_t)B * XPB;          // 2392064
    constexpr size_t WSZ = (size_t)DIM * DIM;        // 65536
    unsigned short* p = (unsigned short*)d_ws;
    unsigned short* xh = p;  p += SZ;
    unsigned short* xph = p; p += XSZ;  // permuted xn (K/V operand)
    unsigned short* qb = p;  p += SZ;
    unsigned short* kc = p;  p += CSZ;
    unsigned short* vc = p;  p += CSZ;
    unsigned short* ah = p;  p += SZ;   // attn out hi (only)
    unsigned short* wth = p; p += 4 * WSZ;
    unsigned short* wtl = p; p += 4 * WSZ;
    float* vm = (float*)p;                       // B*NH*32 fp32
    int* ncp = (int*)(vm + (size_t)B * NH * 32); // B*2
    int* fwd = ncp + 2 * B;                      // M ints

    scan_kernel<<<B, 256, 0, stream>>>(mask, ncp, fwd, vm, xph);

    prep2<<<2560, 256, 0, stream>>>(
        x, ln_g, ln_b, fwd, Wq, Wk, Wv, Wp, wth, wtl, xh, xph);

    gemm_qkv<<<dim3(608, 1, 3), 256, 0, stream>>>(
        xh, xph, wth, bq, bk, bv, ncp, qb, kc, vc, vm);

    attn_kernel<<<dim3(N / 32, B * NH), 128, 0, stream>>>(
        qb, kc, vc, ncp, vm, ah);

    gemm_p<<<dim3(DIM / 16, M / 128), 256, 0, stream>>>(
        ah, wth, wtl, bp, out);
}

// Round 5
// 146.317 us; speedup vs baseline: 1.0406x; 1.0121x over previous
//
#include <hip/hip_runtime.h>
#include <math.h>

typedef __attribute__((ext_vector_type(8))) short short8;
typedef __attribute__((ext_vector_type(4))) float f32x4;

#if __has_builtin(__builtin_amdgcn_exp2f)
#define EXP2F(x) __builtin_amdgcn_exp2f(x)
#else
#define EXP2F(x) exp2f(x)
#endif

constexpr int B   = 4;
constexpr int N   = 2304;
constexpr int DIM = 256;
constexpr int NH  = 8;
constexpr int DH  = 32;
constexpr int M   = B * N;          // 9216 rows
constexpr int SLOTS = 2336;         // N + 32: kept keys + pad + masked keys
constexpr int CST = SLOTS * DH;     // per-(b,h) compact K/V element count
constexpr float LOG2E = 1.44269504088896f;

// float -> bf16 round-to-nearest-even, and back
__device__ inline unsigned short f2bf(float f) {
    union { float f; unsigned u; } c; c.f = f;
    unsigned u = c.u;
    u += 0x7fffu + ((u >> 16) & 1u);
    return (unsigned short)(u >> 16);
}
__device__ inline float bf2f(unsigned short h) {
    union { unsigned u; float f; } c; c.u = ((unsigned)h) << 16;
    return c.f;
}

// ---- FragTile layouts: element (row r, contraction k) stored so an MFMA
// A/B-frag load (16 rows x 32 k) is ONE contiguous 1KB wave transaction.
__device__ inline size_t fo256(int r, int k) {   // [R x 256] tensors
    return ((size_t)((r >> 4) * 8 + (k >> 5)) << 9)
         + (size_t)(((((k & 31) >> 3) << 4) + (r & 15)) * 8 + (k & 7));
}
__device__ inline size_t foQK(int n, int d) {    // per-(b,h) [rows x 32]
    return ((size_t)(n >> 4) << 9)
         + (size_t)((((d >> 3) << 4) + (n & 15)) * 8 + (d & 7));
}
// K with even/odd interleave: within each 32-slot chunk, even slots fill the
// first 16-tile, odd slots the second -> packed b32 LDS writes in attn.
__device__ inline size_t foKI(int slot, int d) {
    int tile = ((slot >> 5) << 1) + (slot & 1);
    int npos = (slot & 31) >> 1;
    return ((size_t)tile << 9)
         + (size_t)((((d >> 3) << 4) + npos) * 8 + (d & 7));
}
__device__ inline size_t foVTC(int d, int key) { // per-(b,h) [32 x SLOTS]
    return ((size_t)((d >> 4) * (SLOTS / 32) + (key >> 5)) << 9)
         + (size_t)(((((key & 31) >> 3) << 4) + (d & 15)) * 8 + (key & 7));
}

// ---- prep: LN (bx<2304) | weight transpose/split | mask scan (2 passes) ---
// xph is GONE: K/V GEMM epilogues scatter through fwd instead, so the scan
// has no downstream in-this-kernel consumer and merges back here (4 blocks).
// Scan also zeroes vm and the <=31 pad ROWS of vc (keys in [Nc,Nkp) that no
// original key maps to; attn multiplies them by p=0 but 0*garbage could be
// NaN, so they must be finite).
__global__ __launch_bounds__(256) void prep_kernel(
    const float* __restrict__ x, const float* __restrict__ g,
    const float* __restrict__ bta, unsigned short* __restrict__ xh,
    const float* __restrict__ Wq, const float* __restrict__ Wk,
    const float* __restrict__ Wv, const float* __restrict__ Wp,
    unsigned short* __restrict__ Wth, unsigned short* __restrict__ Wtl,
    const float* __restrict__ mask, int* __restrict__ ncp,
    int* __restrict__ fwd, float* __restrict__ vm,
    unsigned short* __restrict__ vc)
{
    __shared__ float tbuf[32][33];
    __shared__ int wcnt[9][4];
    __shared__ unsigned long long wbal[9][4];
    int bx = blockIdx.x;
    int t = threadIdx.x;
    int wave = t >> 6, lane = t & 63;
    if (bx < 2304) {
        // ---- LayerNorm, one wave per row -> xh only ----
        int row = bx * 4 + wave;
        float4 v = *(const float4*)&x[(size_t)row * DIM + lane * 4];
        float s = v.x + v.y + v.z + v.w;
        #pragma unroll
        for (int o = 32; o > 0; o >>= 1) s += __shfl_xor(s, o, 64);
        float mu = s * (1.0f / DIM);
        float d0 = v.x - mu, d1 = v.y - mu, d2 = v.z - mu, d3 = v.w - mu;
        float s2 = d0 * d0 + d1 * d1 + d2 * d2 + d3 * d3;
        #pragma unroll
        for (int o = 32; o > 0; o >>= 1) s2 += __shfl_xor(s2, o, 64);
        float r = rsqrtf(s2 * (1.0f / DIM) + 1e-5f);
        float4 gg = *(const float4*)&g[lane * 4];
        float4 bb = *(const float4*)&bta[lane * 4];
        ushort4 hi;
        hi.x = f2bf(d0 * r * gg.x + bb.x);
        hi.y = f2bf(d1 * r * gg.y + bb.y);
        hi.z = f2bf(d2 * r * gg.z + bb.z);
        hi.w = f2bf(d3 * r * gg.w + bb.w);
        *(ushort4*)&xh[fo256(row, lane * 4)] = hi;
    } else if (bx < 2560) {
        // ---- weight transpose + hi/lo split (lo used only by gemm_p) ----
        int idx = bx - 2304;
        int z = idx >> 6, w = idx & 63;
        const float* W = (z == 0) ? Wq : (z == 1) ? Wk : (z == 2) ? Wv : Wp;
        unsigned short* oh = Wth + (size_t)z * DIM * DIM;
        unsigned short* ol = Wtl + (size_t)z * DIM * DIM;
        int tx = t & 31, ty0 = t >> 5;
        int n0 = (w & 7) * 32, k0 = (w >> 3) * 32;
        for (int ty = ty0; ty < 32; ty += 8)
            tbuf[ty][tx] = W[(size_t)(k0 + ty) * DIM + n0 + tx];
        __syncthreads();
        for (int nn = ty0; nn < 32; nn += 8) {
            float v = tbuf[tx][nn];          // = Wt[n0+nn][k0+tx]
            unsigned short hh = f2bf(v);
            size_t o = fo256(n0 + nn, k0 + tx);
            oh[o] = hh;
            ol[o] = f2bf(v - bf2f(hh));
        }
    } else {
        // ---- mask scan, two-pass, one barrier (one block per batch) ----
        int b = bx - 2560;
        vm[b * 256 + t] = 0.f;               // vm is B*NH*32 = 1024 floats
        #pragma unroll
        for (int c = 0; c < 9; ++c) {
            int j = c * 256 + t;
            bool keep = mask[(size_t)b * N + j] > 0.f;
            unsigned long long bal = __ballot(keep);
            if (lane == 0) { wcnt[c][wave] = __popcll(bal); wbal[c][wave] = bal; }
        }
        __syncthreads();
        int Nc = 0;
        #pragma unroll
        for (int c = 0; c < 9; ++c)
            Nc += wcnt[c][0] + wcnt[c][1] + wcnt[c][2] + wcnt[c][3];
        int Nkp = (Nc + 31) & ~31;
        if (t == 0) { ncp[b * 2] = Nc; ncp[b * 2 + 1] = Nkp; }
        int base = 0;
        #pragma unroll
        for (int c = 0; c < 9; ++c) {
            int wb = base;
            for (int w = 0; w < wave; ++w) wb += wcnt[c][w];
            unsigned long long bal = wbal[c][wave];
            bool keep = (bal >> lane) & 1ull;
            int pos = __popcll(bal & ((1ull << lane) - 1ull));
            int keptBefore = wb + pos;
            int j = c * 256 + t;
            fwd[(size_t)b * N + j] = keep ? keptBefore : Nkp + (j - keptBefore);
            base += wcnt[c][0] + wcnt[c][1] + wcnt[c][2] + wcnt[c][3];
        }
        // zero vc pad rows (keys [Nc, Nkp), all 8 heads x 32 d)
        int npad = Nkp - Nc;
        for (int u = t; u < npad * 256; u += 256) {
            int pi = u >> 8;
            int hd = u & 255;
            int h = hd >> 5, d = hd & 31;
            vc[(size_t)(b * NH + h) * CST + foVTC(d, Nc + pi)] = 0;
        }
    }
}

// -------- fused Q/K/V MFMA GEMM, 1-pass bf16 (R12 tiles, 8 waves/EU) -------
// All three z read xh in ORIGINAL row order; K/V epilogues permute on the
// way out through fwd (the stores were per-element scatters already).
// z=0: Q, PRE-SCALED by log2(e). z=1: K -> kc[foKI(fwd[n],d)] iff slot<Nkp.
// z=2: V^T -> vc[foVTC(d,fwd[n])] for kept keys; masked keys' V row-summed
// into vm[] (always-reduce + nonzero-guarded atomic).
__global__ __launch_bounds__(256, 8) void gemm_qkv(
    const unsigned short* __restrict__ xh,
    const unsigned short* __restrict__ Wth,
    const float* __restrict__ bq, const float* __restrict__ bk,
    const float* __restrict__ bv, const int* __restrict__ ncp,
    const int* __restrict__ fwd,
    unsigned short* __restrict__ qb, unsigned short* __restrict__ kc,
    unsigned short* __restrict__ vc, float* __restrict__ vm)
{
    constexpr size_t WSZ = (size_t)DIM * DIM;
    int z = blockIdx.z, bx = blockIdx.x;   // bx in [0,576) for all z
    int tid = threadIdx.x;
    int wave = tid >> 6, lane = tid & 63;
    int quad = lane >> 4, l16 = lane & 15;
    const unsigned short *PA, *PB;
    int arow0, brow0, b;
    if (z == 2) {
        int nidx = bx % 288;
        b = nidx / 72;
        arow0 = (bx / 288) * 128 + wave * 32;   // c-dim (256)
        brow0 = b * N + (nidx % 72) * 32;       // absolute key rows in xh
        PA = Wth + 2 * WSZ;
        PB = xh;
    } else {
        arow0 = (bx >> 3) * 128 + wave * 32;    // absolute rows in xh
        brow0 = (bx & 7) * 32;
        b = arow0 / N;
        PA = xh;
        PB = Wth + (size_t)z * WSZ;
    }
    f32x4 acc[2][2] = {};
    #pragma unroll
    for (int k0 = 0; k0 < DIM; k0 += 32) {
        size_t at = (((size_t)(arow0 >> 4) * 8 + (k0 >> 5)) << 9) + lane * 8;
        size_t bt = (((size_t)(brow0 >> 4) * 8 + (k0 >> 5)) << 9) + lane * 8;
        short8 a0 = *(const short8*)&PA[at];
        short8 a1 = *(const short8*)&PA[at + 4096];
        short8 b0 = *(const short8*)&PB[bt];
        short8 b1 = *(const short8*)&PB[bt + 4096];
        acc[0][0] = __builtin_amdgcn_mfma_f32_16x16x32_bf16(a0, b0, acc[0][0], 0, 0, 0);
        acc[0][1] = __builtin_amdgcn_mfma_f32_16x16x32_bf16(a0, b1, acc[0][1], 0, 0, 0);
        acc[1][0] = __builtin_amdgcn_mfma_f32_16x16x32_bf16(a1, b0, acc[1][0], 0, 0, 0);
        acc[1][1] = __builtin_amdgcn_mfma_f32_16x16x32_bf16(a1, b1, acc[1][1], 0, 0, 0);
    }
    if (z == 0) {
        int nbase = arow0 - b * N;
        #pragma unroll
        for (int j = 0; j < 2; ++j) {
            int c = brow0 + j * 16 + l16;
            int h = c >> 5, d = c & 31;
            float bs = bq[c];
            unsigned short* ob = qb + (size_t)(b * NH + h) * ((size_t)N * DH);
            #pragma unroll
            for (int i = 0; i < 2; ++i)
            #pragma unroll
            for (int r = 0; r < 4; ++r) {
                int n = nbase + i * 16 + quad * 4 + r;
                ob[foQK(n, d)] = f2bf((acc[i][j][r] + bs) * LOG2E);
            }
        }
    } else if (z == 1) {
        int Nkp = ncp[b * 2 + 1];
        #pragma unroll
        for (int i = 0; i < 2; ++i) {
            int4 f4 = *(const int4*)&fwd[arow0 + i * 16 + quad * 4];
            #pragma unroll
            for (int j = 0; j < 2; ++j) {
                int c = brow0 + j * 16 + l16;
                int h = c >> 5, d = c & 31;
                float bs = bk[c];
                unsigned short* ob = kc + (size_t)(b * NH + h) * CST;
                #pragma unroll
                for (int r = 0; r < 4; ++r) {
                    int slot = (&f4.x)[r];
                    if (slot < Nkp) ob[foKI(slot, d)] = f2bf(acc[i][j][r] + bs);
                }
            }
        }
    } else {
        int Nkp = ncp[b * 2 + 1];
        int s0 = fwd[brow0 + l16];             // slot of key j=0
        int s1 = fwd[brow0 + 16 + l16];        // slot of key j=1
        #pragma unroll
        for (int i = 0; i < 2; ++i)
        #pragma unroll
        for (int r = 0; r < 4; ++r) {
            int m = arow0 + i * 16 + quad * 4 + r;
            int h = m >> 5, d = m & 31;
            float bs = bv[m];
            unsigned short* ob = vc + (size_t)(b * NH + h) * CST;
            float vsum = 0.f;
            #pragma unroll
            for (int j = 0; j < 2; ++j) {
                int slot = j ? s1 : s0;
                float val = acc[i][j][r] + bs;
                if (slot < Nkp) ob[foVTC(d, slot)] = f2bf(val);
                else vsum += val;
            }
            vsum += __shfl_xor(vsum, 1, 64);
            vsum += __shfl_xor(vsum, 2, 64);
            vsum += __shfl_xor(vsum, 4, 64);
            vsum += __shfl_xor(vsum, 8, 64);
            if (l16 == 0 && vsum != 0.f)
                atomicAdd(&vm[(size_t)(b * NH + h) * 32 + d], vsum);
        }
    }
}

// ------ MFMA flash attention, IN-BLOCK key split (2 waves, no partials) ----
// Q pre-scaled by log2e -> p = exp2(s). K tiles interleaved (foKI).
// 128-thread blocks: wave kh=0/1 each cover half the key range [0,Nkp) for
// the SAME 32-q-row tile, then combine o/l through 6KB LDS (one barrier).
// P packed to bf16 with v_cvt_pk_bf16_f32 (1 VALU/pair vs 3 bit-ops, RNE).
// Epilogue folds vm + 1/l and writes ah directly in fo256 FragTile layout.
__global__ __launch_bounds__(128, 4) void attn_kernel(
    const unsigned short* __restrict__ Qb,
    const unsigned short* __restrict__ Kc,
    const unsigned short* __restrict__ Vc,
    const int* __restrict__ ncp,
    const float* __restrict__ vm,
    unsigned short* __restrict__ ah)
{
    __shared__ unsigned short pbuf[2 * 2 * 640];   // (wave,tile) x 16 x 40
    __shared__ float cbuf[64 * 24];                // cross-wave o/l exchange
    int tid  = threadIdx.x;
    int kh   = tid >> 6, lane = tid & 63;
    int quad = lane >> 4, l16 = lane & 15;
    int bh = blockIdx.y, b = bh >> 3, h = bh & 7;

    int q0 = blockIdx.x * 32;
    const unsigned short* Qf = Qb + (size_t)bh * ((size_t)N * DH);
    const unsigned short* Kf = Kc + (size_t)bh * CST;
    const unsigned short* Vf = Vc + (size_t)bh * CST;

    int Nc  = ncp[b * 2];
    int Nkp = ncp[b * 2 + 1];
    int chunks = Nkp >> 5;
    int kbeg = ((chunks * kh) >> 1) << 5;
    int kend = ((chunks * (kh + 1)) >> 1) << 5;

    short8 qA0 = *(const short8*)&Qf[((size_t)(q0 >> 4) << 9) + lane * 8];
    short8 qA1 = *(const short8*)&Qf[((size_t)((q0 >> 4) + 1) << 9) + lane * 8];

    f32x4 o00 = {0,0,0,0}, o01 = {0,0,0,0}, o10 = {0,0,0,0}, o11 = {0,0,0,0};
    float l0[4] = {0,0,0,0}, l1[4] = {0,0,0,0};

    unsigned short* pb0 = &pbuf[(kh * 2 + 0) * 640];
    unsigned short* pb1 = &pbuf[(kh * 2 + 1) * 640];

    short8 kB0 = *(const short8*)&Kf[((size_t)(kbeg >> 4) << 9) + lane * 8];
    short8 kB1 = *(const short8*)&Kf[((size_t)((kbeg >> 4) + 1) << 9) + lane * 8];
    short8 vB0 = *(const short8*)&Vf[((size_t)(kbeg >> 5) << 9) + lane * 8];
    short8 vB1 = *(const short8*)&Vf[((size_t)((SLOTS / 32) + (kbeg >> 5)) << 9) + lane * 8];

    for (int k0 = kbeg; k0 < kend; k0 += 32) {
        int kn = (k0 + 32 < kend) ? k0 + 32 : kbeg;   // branchless wrap prefetch
        short8 nk0 = *(const short8*)&Kf[((size_t)(kn >> 4) << 9) + lane * 8];
        short8 nk1 = *(const short8*)&Kf[((size_t)((kn >> 4) + 1) << 9) + lane * 8];
        short8 nv0 = *(const short8*)&Vf[((size_t)(kn >> 5) << 9) + lane * 8];
        short8 nv1 = *(const short8*)&Vf[((size_t)((SLOTS / 32) + (kn >> 5)) << 9) + lane * 8];

        int key0 = k0 + 2 * l16;
        bool in0 = key0 < Nc;                // pad slots -> p = 0 (exact)
        bool in1 = key0 + 1 < Nc;
        f32x4 z = {0,0,0,0};
        f32x4 s00 = __builtin_amdgcn_mfma_f32_16x16x32_bf16(qA0, kB0, z, 0, 0, 0);
        f32x4 s01 = __builtin_amdgcn_mfma_f32_16x16x32_bf16(qA0, kB1, z, 0, 0, 0);
        f32x4 s10 = __builtin_amdgcn_mfma_f32_16x16x32_bf16(qA1, kB0, z, 0, 0, 0);
        f32x4 s11 = __builtin_amdgcn_mfma_f32_16x16x32_bf16(qA1, kB1, z, 0, 0, 0);
        #pragma unroll
        for (int r = 0; r < 4; ++r) {
            int row = quad * 4 + r;
            float p00 = in0 ? EXP2F(s00[r]) : 0.f;
            float p01 = in1 ? EXP2F(s01[r]) : 0.f;
            float p10 = in0 ? EXP2F(s10[r]) : 0.f;
            float p11 = in1 ? EXP2F(s11[r]) : 0.f;
            l0[r] += p00 + p01;
            l1[r] += p10 + p11;
            unsigned pk0, pk1;
            asm("v_cvt_pk_bf16_f32 %0, %1, %2" : "=v"(pk0) : "v"(p00), "v"(p01));
            asm("v_cvt_pk_bf16_f32 %0, %1, %2" : "=v"(pk1) : "v"(p10), "v"(p11));
            *(unsigned*)&pb0[row * 40 + 2 * l16] = pk0;
            *(unsigned*)&pb1[row * 40 + 2 * l16] = pk1;
        }
        short8 pA0 = *(const short8*)&pb0[l16 * 40 + quad * 8];
        short8 pA1 = *(const short8*)&pb1[l16 * 40 + quad * 8];
        o00 = __builtin_amdgcn_mfma_f32_16x16x32_bf16(pA0, vB0, o00, 0, 0, 0);
        o01 = __builtin_amdgcn_mfma_f32_16x16x32_bf16(pA0, vB1, o01, 0, 0, 0);
        o10 = __builtin_amdgcn_mfma_f32_16x16x32_bf16(pA1, vB0, o10, 0, 0, 0);
        o11 = __builtin_amdgcn_mfma_f32_16x16x32_bf16(pA1, vB1, o11, 0, 0, 0);

        kB0 = nk0; kB1 = nk1; vB0 = nv0; vB1 = nv1;
    }
    #pragma unroll
    for (int r = 0; r < 4; ++r) {
        #pragma unroll
        for (int off = 1; off < 16; off <<= 1) {
            l0[r] += __shfl_xor(l0[r], off, 64);
            l1[r] += __shfl_xor(l1[r], off, 64);
        }
    }
    // ---- cross-wave combine through LDS ----
    if (kh == 1) {
        float* cb = &cbuf[lane * 24];
        *(f32x4*)&cb[0]  = o00;
        *(f32x4*)&cb[4]  = o01;
        *(f32x4*)&cb[8]  = o10;
        *(f32x4*)&cb[12] = o11;
        #pragma unroll
        for (int r = 0; r < 4; ++r) { cb[16 + r] = l0[r]; cb[20 + r] = l1[r]; }
    }
    __syncthreads();
    if (kh == 1) return;
    {
        float* cb = &cbuf[lane * 24];
        o00 += *(f32x4*)&cb[0];
        o01 += *(f32x4*)&cb[4];
        o10 += *(f32x4*)&cb[8];
        o11 += *(f32x4*)&cb[12];
        #pragma unroll
        for (int r = 0; r < 4; ++r) { l0[r] += cb[16 + r]; l1[r] += cb[20 + r]; }
    }
    // ---- fused combine: + masked analytic part, normalize, store fo256 ----
    float vm0 = vm[bh * 32 + l16];
    float vm1 = vm[bh * 32 + 16 + l16];
    float lext = (float)(N - Nc);            // masked cols: exp(0)=1 each
    #pragma unroll
    for (int r = 0; r < 4; ++r) {
        int row = quad * 4 + r;
        float ia = 1.f / (l0[r] + lext);
        float ib = 1.f / (l1[r] + lext);
        int ra = b * N + q0 + row;
        int rb = ra + 16;
        ah[fo256(ra, h * 32 + l16)]      = f2bf((o00[r] + vm0) * ia);
        ah[fo256(ra, h * 32 + 16 + l16)] = f2bf((o01[r] + vm1) * ia);
        ah[fo256(rb, h * 32 + l16)]      = f2bf((o10[r] + vm0) * ib);
        ah[fo256(rb, h * 32 + 16 + l16)] = f2bf((o11[r] + vm1) * ib);
    }
}

// --------- final projection GEMM (2-pass: ah*bh + ah*bl): fp32 out ---------
__global__ __launch_bounds__(256, 8) void gemm_p(
    const unsigned short* __restrict__ Ahi,
    const unsigned short* __restrict__ Wth, const unsigned short* __restrict__ Wtl,
    const float* __restrict__ bias, float* __restrict__ out)
{
    constexpr size_t WSZ = (size_t)DIM * DIM;
    const unsigned short* Bhi = Wth + 3 * WSZ;
    const unsigned short* Blo = Wtl + 3 * WSZ;
    int tid = threadIdx.x;
    int wave = tid >> 6, lane = tid & 63;
    int quad = lane >> 4, l16 = lane & 15;
    int r0 = blockIdx.y * 128 + wave * 32;
    int c0 = blockIdx.x * 16;
    f32x4 acc0 = {}, acc1 = {};
    #pragma unroll
    for (int k0 = 0; k0 < DIM; k0 += 32) {
        size_t at = (((size_t)(r0 >> 4) * 8 + (k0 >> 5)) << 9) + lane * 8;
        size_t bt = (((size_t)(c0 >> 4) * 8 + (k0 >> 5)) << 9) + lane * 8;
        short8 ah0 = *(const short8*)&Ahi[at];
        short8 ah1 = *(const short8*)&Ahi[at + 4096];
        short8 bh = *(const short8*)&Bhi[bt];
        short8 bl = *(const short8*)&Blo[bt];
        acc0 = __builtin_amdgcn_mfma_f32_16x16x32_bf16(ah0, bh, acc0, 0, 0, 0);
        acc0 = __builtin_amdgcn_mfma_f32_16x16x32_bf16(ah0, bl, acc0, 0, 0, 0);
        acc1 = __builtin_amdgcn_mfma_f32_16x16x32_bf16(ah1, bh, acc1, 0, 0, 0);
        acc1 = __builtin_amdgcn_mfma_f32_16x16x32_bf16(ah1, bl, acc1, 0, 0, 0);
    }
    int c = c0 + l16;
    float bs = bias[c];
    #pragma unroll
    for (int r = 0; r < 4; ++r) {
        int R0 = r0 + quad * 4 + r;
        out[(size_t)R0 * DIM + c] = acc0[r] + bs;
        out[(size_t)(R0 + 16) * DIM + c] = acc1[r] + bs;
    }
}

extern "C" void kernel_launch(void* const* d_in, const int* in_sizes, int n_in,
                              void* d_out, int out_size, void* d_ws, size_t ws_size,
                              hipStream_t stream)
{
    const float* x    = (const float*)d_in[0];
    const float* mask = (const float*)d_in[1];
    const float* ln_g = (const float*)d_in[2];
    const float* ln_b = (const float*)d_in[3];
    const float* Wq   = (const float*)d_in[4];
    const float* bq   = (const float*)d_in[5];
    const float* Wk   = (const float*)d_in[6];
    const float* bk   = (const float*)d_in[7];
    const float* Wv   = (const float*)d_in[8];
    const float* bv   = (const float*)d_in[9];
    const float* Wp   = (const float*)d_in[10];
    const float* bp   = (const float*)d_in[11];
    float* out = (float*)d_out;

    constexpr size_t SZ  = (size_t)M * DIM;          // 2359296
    constexpr size_t CSZ = (size_t)B * NH * CST;     // 2392064
    constexpr size_t WSZ = (size_t)DIM * DIM;        // 65536
    unsigned short* p = (unsigned short*)d_ws;
    unsigned short* xh = p;  p += SZ;
    unsigned short* qb = p;  p += SZ;
    unsigned short* kc = p;  p += CSZ;
    unsigned short* vc = p;  p += CSZ;
    unsigned short* ah = p;  p += SZ;   // attn out hi (only)
    unsigned short* wth = p; p += 4 * WSZ;
    unsigned short* wtl = p; p += 4 * WSZ;
    float* vm = (float*)p;                       // B*NH*32 fp32
    int* ncp = (int*)(vm + (size_t)B * NH * 32); // B*2
    int* fwd = ncp + 2 * B;                      // M ints

    prep_kernel<<<2564, 256, 0, stream>>>(
        x, ln_g, ln_b, xh, Wq, Wk, Wv, Wp, wth, wtl, mask, ncp, fwd, vm, vc);

    gemm_qkv<<<dim3(576, 1, 3), 256, 0, stream>>>(
        xh, wth, bq, bk, bv, ncp, fwd, qb, kc, vc, vm);

    attn_kernel<<<dim3(N / 32, B * NH), 128, 0, stream>>>(
        qb, kc, vc, ncp, vm, ah);

    gemm_p<<<dim3(DIM / 16, M / 128), 256, 0, stream>>>(
        ah, wth, wtl, bp, out);
}

// Round 7
// 144.092 us; speedup vs baseline: 1.0566x; 1.0154x over previous
//
#include <hip/hip_runtime.h>
#include <math.h>

typedef __attribute__((ext_vector_type(8))) short short8;
typedef __attribute__((ext_vector_type(4))) float f32x4;

#if __has_builtin(__builtin_amdgcn_exp2f)
#define EXP2F(x) __builtin_amdgcn_exp2f(x)
#else
#define EXP2F(x) exp2f(x)
#endif

constexpr int B   = 4;
constexpr int N   = 2304;
constexpr int DIM = 256;
constexpr int NH  = 8;
constexpr int DH  = 32;
constexpr int M   = B * N;          // 9216 rows
constexpr int SLOTS = 2336;         // N + 32: kept keys + pad + masked keys
constexpr int CST = SLOTS * DH;     // per-(b,h) compact K/V element count
constexpr float LOG2E = 1.44269504088896f;

// float -> bf16 round-to-nearest-even, and back
__device__ inline unsigned short f2bf(float f) {
    union { float f; unsigned u; } c; c.f = f;
    unsigned u = c.u;
    u += 0x7fffu + ((u >> 16) & 1u);
    return (unsigned short)(u >> 16);
}
__device__ inline float bf2f(unsigned short h) {
    union { unsigned u; float f; } c; c.u = ((unsigned)h) << 16;
    return c.f;
}

// ---- FragTile layouts: element (row r, contraction k) stored so an MFMA
// A/B-frag load (16 rows x 32 k) is ONE contiguous 1KB wave transaction.
__device__ inline size_t fo256(int r, int k) {   // [R x 256] tensors
    return ((size_t)((r >> 4) * 8 + (k >> 5)) << 9)
         + (size_t)(((((k & 31) >> 3) << 4) + (r & 15)) * 8 + (k & 7));
}
__device__ inline size_t foQK(int n, int d) {    // per-(b,h) [rows x 32]
    return ((size_t)(n >> 4) << 9)
         + (size_t)((((d >> 3) << 4) + (n & 15)) * 8 + (d & 7));
}
// K with even/odd interleave: within each 32-slot chunk, even slots fill the
// first 16-tile, odd slots the second -> packed b32 LDS writes in attn.
__device__ inline size_t foKI(int slot, int d) {
    int tile = ((slot >> 5) << 1) + (slot & 1);
    int npos = (slot & 31) >> 1;
    return ((size_t)tile << 9)
         + (size_t)((((d >> 3) << 4) + npos) * 8 + (d & 7));
}
__device__ inline size_t foVTC(int d, int key) { // per-(b,h) [32 x SLOTS]
    return ((size_t)((d >> 4) * (SLOTS / 32) + (key >> 5)) << 9)
         + (size_t)(((((key & 31) >> 3) << 4) + (d & 15)) * 8 + (key & 7));
}

// ---- prep: LN (bx<2304) | weight transpose/split | mask scan (2 passes) ---
// Scan zeroes vm and the <=31 PAD rows of vc (slots [Nc,Nkp) no original key
// maps to; attn multiplies them by p=0 but 0*garbage could be NaN, so they
// must be finite).
__global__ __launch_bounds__(256) void prep_kernel(
    const float* __restrict__ x, const float* __restrict__ g,
    const float* __restrict__ bta, unsigned short* __restrict__ xh,
    const float* __restrict__ Wq, const float* __restrict__ Wk,
    const float* __restrict__ Wv, const float* __restrict__ Wp,
    unsigned short* __restrict__ Wth, unsigned short* __restrict__ Wtl,
    const float* __restrict__ mask, int* __restrict__ ncp,
    int* __restrict__ fwd, float* __restrict__ vm,
    unsigned short* __restrict__ vc)
{
    __shared__ float tbuf[32][33];
    __shared__ int wcnt[9][4];
    __shared__ unsigned long long wbal[9][4];
    int bx = blockIdx.x;
    int t = threadIdx.x;
    int wave = t >> 6, lane = t & 63;
    if (bx < 2304) {
        // ---- LayerNorm, one wave per row -> xh only ----
        int row = bx * 4 + wave;
        float4 v = *(const float4*)&x[(size_t)row * DIM + lane * 4];
        float s = v.x + v.y + v.z + v.w;
        #pragma unroll
        for (int o = 32; o > 0; o >>= 1) s += __shfl_xor(s, o, 64);
        float mu = s * (1.0f / DIM);
        float d0 = v.x - mu, d1 = v.y - mu, d2 = v.z - mu, d3 = v.w - mu;
        float s2 = d0 * d0 + d1 * d1 + d2 * d2 + d3 * d3;
        #pragma unroll
        for (int o = 32; o > 0; o >>= 1) s2 += __shfl_xor(s2, o, 64);
        float r = rsqrtf(s2 * (1.0f / DIM) + 1e-5f);
        float4 gg = *(const float4*)&g[lane * 4];
        float4 bb = *(const float4*)&bta[lane * 4];
        ushort4 hi;
        hi.x = f2bf(d0 * r * gg.x + bb.x);
        hi.y = f2bf(d1 * r * gg.y + bb.y);
        hi.z = f2bf(d2 * r * gg.z + bb.z);
        hi.w = f2bf(d3 * r * gg.w + bb.w);
        *(ushort4*)&xh[fo256(row, lane * 4)] = hi;
    } else if (bx < 2560) {
        // ---- weight transpose + hi/lo split (lo used only by gemm_p) ----
        int idx = bx - 2304;
        int z = idx >> 6, w = idx & 63;
        const float* W = (z == 0) ? Wq : (z == 1) ? Wk : (z == 2) ? Wv : Wp;
        unsigned short* oh = Wth + (size_t)z * DIM * DIM;
        unsigned short* ol = Wtl + (size_t)z * DIM * DIM;
        int tx = t & 31, ty0 = t >> 5;
        int n0 = (w & 7) * 32, k0 = (w >> 3) * 32;
        for (int ty = ty0; ty < 32; ty += 8)
            tbuf[ty][tx] = W[(size_t)(k0 + ty) * DIM + n0 + tx];
        __syncthreads();
        for (int nn = ty0; nn < 32; nn += 8) {
            float v = tbuf[tx][nn];          // = Wt[n0+nn][k0+tx]
            unsigned short hh = f2bf(v);
            size_t o = fo256(n0 + nn, k0 + tx);
            oh[o] = hh;
            ol[o] = f2bf(v - bf2f(hh));
        }
    } else {
        // ---- mask scan, two-pass, one barrier (one block per batch) ----
        int b = bx - 2560;
        vm[b * 256 + t] = 0.f;               // vm is B*NH*32 = 1024 floats
        #pragma unroll
        for (int c = 0; c < 9; ++c) {
            int j = c * 256 + t;
            bool keep = mask[(size_t)b * N + j] > 0.f;
            unsigned long long bal = __ballot(keep);
            if (lane == 0) { wcnt[c][wave] = __popcll(bal); wbal[c][wave] = bal; }
        }
        __syncthreads();
        int Nc = 0;
        #pragma unroll
        for (int c = 0; c < 9; ++c)
            Nc += wcnt[c][0] + wcnt[c][1] + wcnt[c][2] + wcnt[c][3];
        int Nkp = (Nc + 31) & ~31;
        if (t == 0) { ncp[b * 2] = Nc; ncp[b * 2 + 1] = Nkp; }
        int base = 0;
        #pragma unroll
        for (int c = 0; c < 9; ++c) {
            int wb = base;
            for (int w = 0; w < wave; ++w) wb += wcnt[c][w];
            unsigned long long bal = wbal[c][wave];
            bool keep = (bal >> lane) & 1ull;
            int pos = __popcll(bal & ((1ull << lane) - 1ull));
            int keptBefore = wb + pos;
            int j = c * 256 + t;
            fwd[(size_t)b * N + j] = keep ? keptBefore : Nkp + (j - keptBefore);
            base += wcnt[c][0] + wcnt[c][1] + wcnt[c][2] + wcnt[c][3];
        }
        // zero vc pad rows (keys [Nc, Nkp), all 8 heads x 32 d)
        int npad = Nkp - Nc;
        for (int u = t; u < npad * 256; u += 256) {
            int pi = u >> 8;
            int hd = u & 255;
            int h = hd >> 5, d = hd & 31;
            vc[(size_t)(b * NH + h) * CST + foVTC(d, Nc + pi)] = 0;
        }
    }
}

// -------- fused Q/K/V MFMA GEMM, 1-pass bf16 (R12 tiles, 8 waves/EU) -------
// All three z read xh in ORIGINAL row order; K/V epilogues permute on the
// way out through fwd. z=0: Q (pre-scaled by log2e), epilogue transposed
// through wave-local LDS so qb stores are 2 coalesced b128 per wave instead
// of 16 scattered 2B per lane. z=1: K -> kc[foKI] iff slot<Nkp. z=2: V^T ->
// vc[foVTC] kept keys; masked keys' V row-summed into vm[].
__global__ __launch_bounds__(256, 8) void gemm_qkv(
    const unsigned short* __restrict__ xh,
    const unsigned short* __restrict__ Wth,
    const float* __restrict__ bq, const float* __restrict__ bk,
    const float* __restrict__ bv, const int* __restrict__ ncp,
    const int* __restrict__ fwd,
    unsigned short* __restrict__ qb, unsigned short* __restrict__ kc,
    unsigned short* __restrict__ vc, float* __restrict__ vm)
{
    __shared__ unsigned short qsm[4 * 2 * 640];  // per-wave Q transpose
    constexpr size_t WSZ = (size_t)DIM * DIM;
    int z = blockIdx.z, bx = blockIdx.x;   // bx in [0,576) for all z
    int tid = threadIdx.x;
    int wave = tid >> 6, lane = tid & 63;
    int quad = lane >> 4, l16 = lane & 15;
    const unsigned short *PA, *PB;
    int arow0, brow0, b;
    if (z == 2) {
        int nidx = bx % 288;
        b = nidx / 72;
        arow0 = (bx / 288) * 128 + wave * 32;   // c-dim (256)
        brow0 = b * N + (nidx % 72) * 32;       // absolute key rows in xh
        PA = Wth + 2 * WSZ;
        PB = xh;
    } else {
        arow0 = (bx >> 3) * 128 + wave * 32;    // absolute rows in xh
        brow0 = (bx & 7) * 32;
        b = arow0 / N;
        PA = xh;
        PB = Wth + (size_t)z * WSZ;
    }
    f32x4 acc[2][2] = {};
    #pragma unroll
    for (int k0 = 0; k0 < DIM; k0 += 32) {
        size_t at = (((size_t)(arow0 >> 4) * 8 + (k0 >> 5)) << 9) + lane * 8;
        size_t bt = (((size_t)(brow0 >> 4) * 8 + (k0 >> 5)) << 9) + lane * 8;
        short8 a0 = *(const short8*)&PA[at];
        short8 a1 = *(const short8*)&PA[at + 4096];
        short8 b0 = *(const short8*)&PB[bt];
        short8 b1 = *(const short8*)&PB[bt + 4096];
        acc[0][0] = __builtin_amdgcn_mfma_f32_16x16x32_bf16(a0, b0, acc[0][0], 0, 0, 0);
        acc[0][1] = __builtin_amdgcn_mfma_f32_16x16x32_bf16(a0, b1, acc[0][1], 0, 0, 0);
        acc[1][0] = __builtin_amdgcn_mfma_f32_16x16x32_bf16(a1, b0, acc[1][0], 0, 0, 0);
        acc[1][1] = __builtin_amdgcn_mfma_f32_16x16x32_bf16(a1, b1, acc[1][1], 0, 0, 0);
    }
    if (z == 0) {
        int nbase = arow0 - b * N;               // multiple of 32
        int h = brow0 >> 5;                      // whole 32-col block = 1 head
        unsigned short* ob = qb + (size_t)(b * NH + h) * ((size_t)N * DH);
        unsigned short* pb0 = &qsm[(wave * 2 + 0) * 640];
        unsigned short* pb1 = &qsm[(wave * 2 + 1) * 640];
        #pragma unroll
        for (int j = 0; j < 2; ++j) {
            int c = brow0 + j * 16 + l16;
            float bs = bq[c];
            #pragma unroll
            for (int r = 0; r < 4; ++r) {
                int rr = quad * 4 + r;
                pb0[rr * 40 + j * 16 + l16] = f2bf((acc[0][j][r] + bs) * LOG2E);
                pb1[rr * 40 + j * 16 + l16] = f2bf((acc[1][j][r] + bs) * LOG2E);
            }
        }
        // wave-local LDS round trip; no barrier needed
        short8 q0 = *(const short8*)&pb0[l16 * 40 + quad * 8];
        short8 q1 = *(const short8*)&pb1[l16 * 40 + quad * 8];
        *(short8*)&ob[((size_t)((nbase >> 4) + 0) << 9) + lane * 8] = q0;
        *(short8*)&ob[((size_t)((nbase >> 4) + 1) << 9) + lane * 8] = q1;
    } else if (z == 1) {
        int Nkp = ncp[b * 2 + 1];
        #pragma unroll
        for (int i = 0; i < 2; ++i) {
            int4 f4 = *(const int4*)&fwd[arow0 + i * 16 + quad * 4];
            #pragma unroll
            for (int j = 0; j < 2; ++j) {
                int c = brow0 + j * 16 + l16;
                int h = c >> 5, d = c & 31;
                float bs = bk[c];
                unsigned short* ob = kc + (size_t)(b * NH + h) * CST;
                #pragma unroll
                for (int r = 0; r < 4; ++r) {
                    int slot = (&f4.x)[r];
                    if (slot < Nkp) ob[foKI(slot, d)] = f2bf(acc[i][j][r] + bs);
                }
            }
        }
    } else {
        int Nkp = ncp[b * 2 + 1];
        int s0 = fwd[brow0 + l16];             // slot of key j=0
        int s1 = fwd[brow0 + 16 + l16];        // slot of key j=1
        #pragma unroll
        for (int i = 0; i < 2; ++i)
        #pragma unroll
        for (int r = 0; r < 4; ++r) {
            int m = arow0 + i * 16 + quad * 4 + r;
            int h = m >> 5, d = m & 31;
            float bs = bv[m];
            unsigned short* ob = vc + (size_t)(b * NH + h) * CST;
            float vsum = 0.f;
            #pragma unroll
            for (int j = 0; j < 2; ++j) {
                int slot = j ? s1 : s0;
                float val = acc[i][j][r] + bs;
                if (slot < Nkp) ob[foVTC(d, slot)] = f2bf(val);
                else vsum += val;
            }
            vsum += __shfl_xor(vsum, 1, 64);
            vsum += __shfl_xor(vsum, 2, 64);
            vsum += __shfl_xor(vsum, 4, 64);
            vsum += __shfl_xor(vsum, 8, 64);
            if (l16 == 0 && vsum != 0.f)
                atomicAdd(&vm[(size_t)(b * NH + h) * 32 + d], vsum);
        }
    }
}

// ------ MFMA flash attention, IN-BLOCK key split (2 waves, no partials) ----
// Q pre-scaled by log2e -> p = exp2(s). K tiles interleaved (foKI).
// 128-thread blocks: wave kh=0/1 each cover half the key range [0,Nkp) for
// the SAME 32-q-row tile, then combine o/l through 6KB LDS (one barrier).
// P packed to bf16 with v_cvt_pk_bf16_f32 (1 VALU/pair vs 3 bit-ops, RNE).
// Epilogue folds vm + 1/l and writes ah directly in fo256 FragTile layout.
__global__ __launch_bounds__(128, 4) void attn_kernel(
    const unsigned short* __restrict__ Qb,
    const unsigned short* __restrict__ Kc,
    const unsigned short* __restrict__ Vc,
    const int* __restrict__ ncp,
    const float* __restrict__ vm,
    unsigned short* __restrict__ ah)
{
    __shared__ unsigned short pbuf[2 * 2 * 640];   // (wave,tile) x 16 x 40
    __shared__ float cbuf[64 * 24];                // cross-wave o/l exchange
    int tid  = threadIdx.x;
    int kh   = tid >> 6, lane = tid & 63;
    int quad = lane >> 4, l16 = lane & 15;
    int bh = blockIdx.y, b = bh >> 3, h = bh & 7;

    int q0 = blockIdx.x * 32;
    const unsigned short* Qf = Qb + (size_t)bh * ((size_t)N * DH);
    const unsigned short* Kf = Kc + (size_t)bh * CST;
    const unsigned short* Vf = Vc + (size_t)bh * CST;

    int Nc  = ncp[b * 2];
    int Nkp = ncp[b * 2 + 1];
    int chunks = Nkp >> 5;
    int kbeg = ((chunks * kh) >> 1) << 5;
    int kend = ((chunks * (kh + 1)) >> 1) << 5;

    short8 qA0 = *(const short8*)&Qf[((size_t)(q0 >> 4) << 9) + lane * 8];
    short8 qA1 = *(const short8*)&Qf[((size_t)((q0 >> 4) + 1) << 9) + lane * 8];

    f32x4 o00 = {0,0,0,0}, o01 = {0,0,0,0}, o10 = {0,0,0,0}, o11 = {0,0,0,0};
    float l0[4] = {0,0,0,0}, l1[4] = {0,0,0,0};

    unsigned short* pb0 = &pbuf[(kh * 2 + 0) * 640];
    unsigned short* pb1 = &pbuf[(kh * 2 + 1) * 640];

    short8 kB0 = *(const short8*)&Kf[((size_t)(kbeg >> 4) << 9) + lane * 8];
    short8 kB1 = *(const short8*)&Kf[((size_t)((kbeg >> 4) + 1) << 9) + lane * 8];
    short8 vB0 = *(const short8*)&Vf[((size_t)(kbeg >> 5) << 9) + lane * 8];
    short8 vB1 = *(const short8*)&Vf[((size_t)((SLOTS / 32) + (kbeg >> 5)) << 9) + lane * 8];

    for (int k0 = kbeg; k0 < kend; k0 += 32) {
        int kn = (k0 + 32 < kend) ? k0 + 32 : kbeg;   // branchless wrap prefetch
        short8 nk0 = *(const short8*)&Kf[((size_t)(kn >> 4) << 9) + lane * 8];
        short8 nk1 = *(const short8*)&Kf[((size_t)((kn >> 4) + 1) << 9) + lane * 8];
        short8 nv0 = *(const short8*)&Vf[((size_t)(kn >> 5) << 9) + lane * 8];
        short8 nv1 = *(const short8*)&Vf[((size_t)((SLOTS / 32) + (kn >> 5)) << 9) + lane * 8];

        int key0 = k0 + 2 * l16;
        bool in0 = key0 < Nc;                // pad slots -> p = 0 (exact)
        bool in1 = key0 + 1 < Nc;
        f32x4 z = {0,0,0,0};
        f32x4 s00 = __builtin_amdgcn_mfma_f32_16x16x32_bf16(qA0, kB0, z, 0, 0, 0);
        f32x4 s01 = __builtin_amdgcn_mfma_f32_16x16x32_bf16(qA0, kB1, z, 0, 0, 0);
        f32x4 s10 = __builtin_amdgcn_mfma_f32_16x16x32_bf16(qA1, kB0, z, 0, 0, 0);
        f32x4 s11 = __builtin_amdgcn_mfma_f32_16x16x32_bf16(qA1, kB1, z, 0, 0, 0);
        #pragma unroll
        for (int r = 0; r < 4; ++r) {
            int row = quad * 4 + r;
            float p00 = in0 ? EXP2F(s00[r]) : 0.f;
            float p01 = in1 ? EXP2F(s01[r]) : 0.f;
            float p10 = in0 ? EXP2F(s10[r]) : 0.f;
            float p11 = in1 ? EXP2F(s11[r]) : 0.f;
            l0[r] += p00 + p01;
            l1[r] += p10 + p11;
            unsigned pk0, pk1;
            asm("v_cvt_pk_bf16_f32 %0, %1, %2" : "=v"(pk0) : "v"(p00), "v"(p01));
            asm("v_cvt_pk_bf16_f32 %0, %1, %2" : "=v"(pk1) : "v"(p10), "v"(p11));
            *(unsigned*)&pb0[row * 40 + 2 * l16] = pk0;
            *(unsigned*)&pb1[row * 40 + 2 * l16] = pk1;
        }
        short8 pA0 = *(const short8*)&pb0[l16 * 40 + quad * 8];
        short8 pA1 = *(const short8*)&pb1[l16 * 40 + quad * 8];
        o00 = __builtin_amdgcn_mfma_f32_16x16x32_bf16(pA0, vB0, o00, 0, 0, 0);
        o01 = __builtin_amdgcn_mfma_f32_16x16x32_bf16(pA0, vB1, o01, 0, 0, 0);
        o10 = __builtin_amdgcn_mfma_f32_16x16x32_bf16(pA1, vB0, o10, 0, 0, 0);
        o11 = __builtin_amdgcn_mfma_f32_16x16x32_bf16(pA1, vB1, o11, 0, 0, 0);

        kB0 = nk0; kB1 = nk1; vB0 = nv0; vB1 = nv1;
    }
    #pragma unroll
    for (int r = 0; r < 4; ++r) {
        #pragma unroll
        for (int off = 1; off < 16; off <<= 1) {
            l0[r] += __shfl_xor(l0[r], off, 64);
            l1[r] += __shfl_xor(l1[r], off, 64);
        }
    }
    // ---- cross-wave combine through LDS ----
    if (kh == 1) {
        float* cb = &cbuf[lane * 24];
        *(f32x4*)&cb[0]  = o00;
        *(f32x4*)&cb[4]  = o01;
        *(f32x4*)&cb[8]  = o10;
        *(f32x4*)&cb[12] = o11;
        #pragma unroll
        for (int r = 0; r < 4; ++r) { cb[16 + r] = l0[r]; cb[20 + r] = l1[r]; }
    }
    __syncthreads();
    if (kh == 1) return;
    {
        float* cb = &cbuf[lane * 24];
        o00 += *(f32x4*)&cb[0];
        o01 += *(f32x4*)&cb[4];
        o10 += *(f32x4*)&cb[8];
        o11 += *(f32x4*)&cb[12];
        #pragma unroll
        for (int r = 0; r < 4; ++r) { l0[r] += cb[16 + r]; l1[r] += cb[20 + r]; }
    }
    // ---- fused combine: + masked analytic part, normalize, store fo256 ----
    float vm0 = vm[bh * 32 + l16];
    float vm1 = vm[bh * 32 + 16 + l16];
    float lext = (float)(N - Nc);            // masked cols: exp(0)=1 each
    #pragma unroll
    for (int r = 0; r < 4; ++r) {
        int row = quad * 4 + r;
        float ia = 1.f / (l0[r] + lext);
        float ib = 1.f / (l1[r] + lext);
        int ra = b * N + q0 + row;
        int rb = ra + 16;
        ah[fo256(ra, h * 32 + l16)]      = f2bf((o00[r] + vm0) * ia);
        ah[fo256(ra, h * 32 + 16 + l16)] = f2bf((o01[r] + vm1) * ia);
        ah[fo256(rb, h * 32 + l16)]      = f2bf((o10[r] + vm0) * ib);
        ah[fo256(rb, h * 32 + 16 + l16)] = f2bf((o11[r] + vm1) * ib);
    }
}

// --------- final projection GEMM (2-pass: ah*bh + ah*bl): fp32 out ---------
__global__ __launch_bounds__(256, 8) void gemm_p(
    const unsigned short* __restrict__ Ahi,
    const unsigned short* __restrict__ Wth, const unsigned short* __restrict__ Wtl,
    const float* __restrict__ bias, float* __restrict__ out)
{
    constexpr size_t WSZ = (size_t)DIM * DIM;
    const unsigned short* Bhi = Wth + 3 * WSZ;
    const unsigned short* Blo = Wtl + 3 * WSZ;
    int tid = threadIdx.x;
    int wave = tid >> 6, lane = tid & 63;
    int quad = lane >> 4, l16 = lane & 15;
    int r0 = blockIdx.y * 128 + wave * 32;
    int c0 = blockIdx.x * 16;
    f32x4 acc0 = {}, acc1 = {};
    #pragma unroll
    for (int k0 = 0; k0 < DIM; k0 += 32) {
        size_t at = (((size_t)(r0 >> 4) * 8 + (k0 >> 5)) << 9) + lane * 8;
        size_t bt = (((size_t)(c0 >> 4) * 8 + (k0 >> 5)) << 9) + lane * 8;
        short8 ah0 = *(const short8*)&Ahi[at];
        short8 ah1 = *(const short8*)&Ahi[at + 4096];
        short8 bh = *(const short8*)&Bhi[bt];
        short8 bl = *(const short8*)&Blo[bt];
        acc0 = __builtin_amdgcn_mfma_f32_16x16x32_bf16(ah0, bh, acc0, 0, 0, 0);
        acc0 = __builtin_amdgcn_mfma_f32_16x16x32_bf16(ah0, bl, acc0, 0, 0, 0);
        acc1 = __builtin_amdgcn_mfma_f32_16x16x32_bf16(ah1, bh, acc1, 0, 0, 0);
        acc1 = __builtin_amdgcn_mfma_f32_16x16x32_bf16(ah1, bl, acc1, 0, 0, 0);
    }
    int c = c0 + l16;
    float bs = bias[c];
    #pragma unroll
    for (int r = 0; r < 4; ++r) {
        int R0 = r0 + quad * 4 + r;
        out[(size_t)R0 * DIM + c] = acc0[r] + bs;
        out[(size_t)(R0 + 16) * DIM + c] = acc1[r] + bs;
    }
}

extern "C" void kernel_launch(void* const* d_in, const int* in_sizes, int n_in,
                              void* d_out, int out_size, void* d_ws, size_t ws_size,
                              hipStream_t stream)
{
    const float* x    = (const float*)d_in[0];
    const float* mask = (const float*)d_in[1];
    const float* ln_g = (const float*)d_in[2];
    const float* ln_b = (const float*)d_in[3];
    const float* Wq   = (const float*)d_in[4];
    const float* bq   = (const float*)d_in[5];
    const float* Wk   = (const float*)d_in[6];
    const float* bk   = (const float*)d_in[7];
    const float* Wv   = (const float*)d_in[8];
    const float* bv   = (const float*)d_in[9];
    const float* Wp   = (const float*)d_in[10];
    const float* bp   = (const float*)d_in[11];
    float* out = (float*)d_out;

    constexpr size_t SZ  = (size_t)M * DIM;          // 2359296
    constexpr size_t CSZ = (size_t)B * NH * CST;     // 2392064
    constexpr size_t WSZ = (size_t)DIM * DIM;        // 65536
    unsigned short* p = (unsigned short*)d_ws;
    unsigned short* xh = p;  p += SZ;
    unsigned short* qb = p;  p += SZ;
    unsigned short* kc = p;  p += CSZ;
    unsigned short* vc = p;  p += CSZ;
    unsigned short* ah = p;  p += SZ;   // attn out hi (only)
    unsigned short* wth = p; p += 4 * WSZ;
    unsigned short* wtl = p; p += 4 * WSZ;
    float* vm = (float*)p;                       // B*NH*32 fp32
    int* ncp = (int*)(vm + (size_t)B * NH * 32); // B*2
    int* fwd = ncp + 2 * B;                      // M ints

    prep_kernel<<<2564, 256, 0, stream>>>(
        x, ln_g, ln_b, xh, Wq, Wk, Wv, Wp, wth, wtl, mask, ncp, fwd, vm, vc);

    gemm_qkv<<<dim3(576, 1, 3), 256, 0, stream>>>(
        xh, wth, bq, bk, bv, ncp, fwd, qb, kc, vc, vm);

    attn_kernel<<<dim3(N / 32, B * NH), 128, 0, stream>>>(
        qb, kc, vc, ncp, vm, ah);

    gemm_p<<<dim3(DIM / 16, M / 128), 256, 0, stream>>>(
        ah, wth, wtl, bp, out);
}